// Round 14
// baseline (267.018 us; speedup 1.0000x reference)
//
#include <hip/hip_runtime.h>
#include <hip/hip_bf16.h>

#define NN 50000
#define NE 800000
#define NSB 49   // scan blocks: 49 * 1024 >= NN
#define AGG_BLOCKS 2048

typedef __attribute__((ext_vector_type(8))) short bh8;
typedef __attribute__((ext_vector_type(4))) float f32x4;

static __device__ __forceinline__ unsigned short f2bf(float f){
  unsigned u = __float_as_uint(f);
  unsigned r = (u + 0x7fffu + ((u >> 16) & 1u)) >> 16;
  return (unsigned short)r;
}
static __device__ __forceinline__ float bflo(unsigned u){ return __uint_as_float(u << 16); }
static __device__ __forceinline__ float bfhi(unsigned u){ return __uint_as_float(u & 0xffff0000u); }
static __device__ __forceinline__ unsigned packbf2(float lo, float hi){
  return ((unsigned)f2bf(hi) << 16) | (unsigned)f2bf(lo);
}
static __device__ __forceinline__ unsigned char f2fp8(float v){
  return (unsigned char)(__builtin_amdgcn_cvt_pk_fp8_f32(v, v, 0, false) & 0xff);
}

// async global->LDS, 16B per lane, LDS dest = wave-uniform base + lane*16
static __device__ __forceinline__ void gload16(const void* g, void* l){
  __builtin_amdgcn_global_load_lds(
      (const __attribute__((address_space(1))) unsigned int*)g,
      (__attribute__((address_space(3))) unsigned int*)l, 16, 0, 0);
}

// ---------------- CSR build ----------------
__global__ void hist_k(const int* __restrict__ dstv, int* __restrict__ cnt,
                       int* __restrict__ rank){
  int i = blockIdx.x * 256 + threadIdx.x;
  if (i < NE) rank[i] = atomicAdd(&cnt[dstv[i]], 1);
}

__global__ __launch_bounds__(256) void scan1_k(const int* __restrict__ cnt,
                                               int* __restrict__ rowp,
                                               int* __restrict__ bsum){
  __shared__ int sa[256], sb[256];
  const int t = threadIdx.x, blk = blockIdx.x;
  const int base = blk * 1024 + t * 4;
  int4 v = make_int4(0, 0, 0, 0);
  if (base + 3 < NN) v = *reinterpret_cast<const int4*>(cnt + base);
  else if (base < NN){
    v.x = cnt[base];
    if (base + 1 < NN) v.y = cnt[base + 1];
    if (base + 2 < NN) v.z = cnt[base + 2];
  }
  const int s = v.x + v.y + v.z + v.w;
  sa[t] = s; __syncthreads();
  int* a = sa; int* b = sb;
  for (int off = 1; off < 256; off <<= 1){
    int val = a[t]; if (t >= off) val += a[t - off];
    b[t] = val; __syncthreads();
    int* tmp = a; a = b; b = tmp;
  }
  const int ex = a[t] - s;             // exclusive prefix within block
  if (base < NN){
    rowp[base] = ex;
    if (base + 1 < NN) rowp[base + 1] = ex + v.x;
    if (base + 2 < NN) rowp[base + 2] = ex + v.x + v.y;
    if (base + 3 < NN) rowp[base + 3] = ex + v.x + v.y + v.z;
  }
  if (t == 255) bsum[blk] = a[255];    // block total
}

__global__ void scan2_k(int* __restrict__ bsum){
  __shared__ int s[64];
  const int t = threadIdx.x;
  s[t] = (t < NSB) ? bsum[t] : 0;
  __syncthreads();
  if (t == 0){
    int run = 0;
    for (int i = 0; i < NSB; ++i){ int c = s[i]; s[i] = run; run += c; }
  }
  __syncthreads();
  if (t < NSB) bsum[t] = s[t];
}

__global__ __launch_bounds__(256) void scan3_k(int* __restrict__ rowp,
                                               const int* __restrict__ bsum){
  const int blk = blockIdx.x;
  const int base = blk * 1024 + threadIdx.x * 4;
  const int off = bsum[blk];
  #pragma unroll
  for (int i = 0; i < 4; ++i){
    int idx = base + i;
    if (idx < NN) rowp[idx] += off;
  }
  if (blk == 0 && threadIdx.x == 0) rowp[NN] = NE;
}

// dst-range-partitioned, ATOMIC-FREE fill: csrc[rowp[d]+rank[i]] = srcv[i].
__global__ __launch_bounds__(256) void fill_k(const int* __restrict__ srcv,
                       const int* __restrict__ dstv,
                       const int* __restrict__ rank,
                       const int* __restrict__ rowp, int* __restrict__ csrc){
  const int part  = blockIdx.x & 7;
  const int chunk = blockIdx.x >> 3;           // 0..127
  const int lo = part * (NN / 8);
  const int hi = lo + (NN / 8);                // NN%8==0
  const int base = chunk * (NE / 128);         // NE%128==0
  const int endi = base + (NE / 128);
  for (int i = base + threadIdx.x; i < endi; i += 256){
    int d = dstv[i];
    if (d >= lo && d < hi){
      csrc[rowp[d] + rank[i]] = srcv[i];
    }
  }
}

// ---------------- conversions / weight prep ----------------
// x f32 -> xb bf16 (GEMM self-term) AND xq fp8 (layer-1 gather table)
__global__ void f2b_k(const float4* __restrict__ x, uint2* __restrict__ xb,
                      unsigned* __restrict__ xq){
  int i = blockIdx.x * 256 + threadIdx.x;
  if (i < NN * 128 / 4){
    float4 v = x[i];
    uint2 o; o.x = packbf2(v.x, v.y); o.y = packbf2(v.z, v.w);
    xb[i] = o;
    int w = 0;
    w = __builtin_amdgcn_cvt_pk_fp8_f32(v.x, v.y, w, false);
    w = __builtin_amdgcn_cvt_pk_fp8_f32(v.z, v.w, w, true);
    xq[i] = (unsigned)w;
  }
}

// B1t[n][k] k<128->wl1, else wr1 ; B2t[n][k] k<256->wl2 else wr2 ;
// B3t[n][k] n<128->wl3 col n, else wr3 col n-128 ; plus BN affine S/T.
__global__ void prep_k(const float* __restrict__ wl1, const float* __restrict__ wr1,
                       const float* __restrict__ wl2, const float* __restrict__ wr2,
                       const float* __restrict__ wl3, const float* __restrict__ wr3,
                       const float* __restrict__ bl1, const float* __restrict__ bl2,
                       const float* __restrict__ bn1w, const float* __restrict__ bn1b,
                       const float* __restrict__ bn1m, const float* __restrict__ bn1v,
                       const float* __restrict__ bn2w, const float* __restrict__ bn2b,
                       const float* __restrict__ bn2m, const float* __restrict__ bn2v,
                       unsigned short* __restrict__ B1t, unsigned short* __restrict__ B2t,
                       unsigned short* __restrict__ B3t,
                       float* __restrict__ S1, float* __restrict__ T1,
                       float* __restrict__ S2, float* __restrict__ T2){
  int i = blockIdx.x * 256 + threadIdx.x;
  if (i < 65536){
    int n = i >> 8, k = i & 255;
    float v = (k < 128) ? wl1[k * 256 + n] : wr1[(k - 128) * 256 + n];
    B1t[n * 256 + k] = f2bf(v);
  } else if (i < 65536 + 131072){
    int j = i - 65536; int n = j >> 9, k = j & 511;
    float v = (k < 256) ? wl2[k * 256 + n] : wr2[(k - 256) * 256 + n];
    B2t[n * 512 + k] = f2bf(v);
  } else if (i < 65536 + 131072 + 65536){
    int j = i - (65536 + 131072); int n = j >> 8, k = j & 255;
    float v = (n < 128) ? wl3[k * 128 + n] : wr3[k * 128 + (n - 128)];
    B3t[n * 256 + k] = f2bf(v);
  } else if (i < 65536 + 131072 + 65536 + 512){
    int j = i - (65536 + 131072 + 65536);
    if (j < 256){
      float s = bn1w[j] * rsqrtf(bn1v[j] + 1e-5f);
      S1[j] = s; T1[j] = (bl1[j] - bn1m[j]) * s + bn1b[j];
    } else {
      int c = j - 256;
      float s = bn2w[c] * rsqrtf(bn2v[c] + 1e-5f);
      S2[c] = s; T2[c] = (bl2[c] - bn2m[c]) * s + bn2b[c];
    }
  }
}

// ---------------- mean aggregation (gather via CSR) ----------------
__global__ __launch_bounds__(256) void agg128q_k(const unsigned short* __restrict__ featq,
                         unsigned* __restrict__ out,
                         const int* __restrict__ rowp, const int* __restrict__ csrc){
  const int lane = threadIdx.x & 63;
  const int node0 = __builtin_amdgcn_readfirstlane(blockIdx.x * 4 + (threadIdx.x >> 6));
  const int nw = gridDim.x * 4;
  for (int node = node0; node < NN; node += nw){
    const int start = rowp[node], end = rowp[node + 1];
    float a0 = 0.f, a1 = 0.f, b0 = 0.f, b1 = 0.f;
    int e = start;
    for (; e + 7 < end; e += 8){
      unsigned u0 = featq[(size_t)csrc[e]     * 64 + lane];
      unsigned u1 = featq[(size_t)csrc[e + 1] * 64 + lane];
      unsigned u2 = featq[(size_t)csrc[e + 2] * 64 + lane];
      unsigned u3 = featq[(size_t)csrc[e + 3] * 64 + lane];
      unsigned u4 = featq[(size_t)csrc[e + 4] * 64 + lane];
      unsigned u5 = featq[(size_t)csrc[e + 5] * 64 + lane];
      unsigned u6 = featq[(size_t)csrc[e + 6] * 64 + lane];
      unsigned u7 = featq[(size_t)csrc[e + 7] * 64 + lane];
      a0 += __builtin_amdgcn_cvt_f32_fp8(u0, 0); a1 += __builtin_amdgcn_cvt_f32_fp8(u0, 1);
      b0 += __builtin_amdgcn_cvt_f32_fp8(u1, 0); b1 += __builtin_amdgcn_cvt_f32_fp8(u1, 1);
      a0 += __builtin_amdgcn_cvt_f32_fp8(u2, 0); a1 += __builtin_amdgcn_cvt_f32_fp8(u2, 1);
      b0 += __builtin_amdgcn_cvt_f32_fp8(u3, 0); b1 += __builtin_amdgcn_cvt_f32_fp8(u3, 1);
      a0 += __builtin_amdgcn_cvt_f32_fp8(u4, 0); a1 += __builtin_amdgcn_cvt_f32_fp8(u4, 1);
      b0 += __builtin_amdgcn_cvt_f32_fp8(u5, 0); b1 += __builtin_amdgcn_cvt_f32_fp8(u5, 1);
      a0 += __builtin_amdgcn_cvt_f32_fp8(u6, 0); a1 += __builtin_amdgcn_cvt_f32_fp8(u6, 1);
      b0 += __builtin_amdgcn_cvt_f32_fp8(u7, 0); b1 += __builtin_amdgcn_cvt_f32_fp8(u7, 1);
    }
    for (; e < end; ++e){
      unsigned u = featq[(size_t)csrc[e] * 64 + lane];
      a0 += __builtin_amdgcn_cvt_f32_fp8(u, 0); a1 += __builtin_amdgcn_cvt_f32_fp8(u, 1);
    }
    int d = end - start;
    float inv = 1.f / (float)(d > 0 ? d : 1);
    out[(size_t)node * 64 + lane] = packbf2((a0 + b0) * inv, (a1 + b1) * inv);
  }
}

#define DEC8(u, x0, x1, x2, x3) { \
  x0 += __builtin_amdgcn_cvt_f32_fp8((u), 0); \
  x1 += __builtin_amdgcn_cvt_f32_fp8((u), 1); \
  x2 += __builtin_amdgcn_cvt_f32_fp8((u), 2); \
  x3 += __builtin_amdgcn_cvt_f32_fp8((u), 3); }

__global__ __launch_bounds__(256) void agg256q_k(const unsigned* __restrict__ featq, unsigned* __restrict__ out,
                         const int* __restrict__ rowp, const int* __restrict__ csrc){
  const int lane = threadIdx.x & 63;
  const int node0 = __builtin_amdgcn_readfirstlane(blockIdx.x * 4 + (threadIdx.x >> 6));
  const int nw = gridDim.x * 4;
  for (int node = node0; node < NN; node += nw){
    const int start = rowp[node], end = rowp[node + 1];
    float a0 = 0.f, a1 = 0.f, a2 = 0.f, a3 = 0.f;
    float b0 = 0.f, b1 = 0.f, b2 = 0.f, b3 = 0.f;
    int e = start;
    for (; e + 7 < end; e += 8){
      unsigned u0 = featq[(size_t)csrc[e]     * 64 + lane];
      unsigned u1 = featq[(size_t)csrc[e + 1] * 64 + lane];
      unsigned u2 = featq[(size_t)csrc[e + 2] * 64 + lane];
      unsigned u3 = featq[(size_t)csrc[e + 3] * 64 + lane];
      unsigned u4 = featq[(size_t)csrc[e + 4] * 64 + lane];
      unsigned u5 = featq[(size_t)csrc[e + 5] * 64 + lane];
      unsigned u6 = featq[(size_t)csrc[e + 6] * 64 + lane];
      unsigned u7 = featq[(size_t)csrc[e + 7] * 64 + lane];
      DEC8(u0, a0, a1, a2, a3) DEC8(u1, b0, b1, b2, b3)
      DEC8(u2, a0, a1, a2, a3) DEC8(u3, b0, b1, b2, b3)
      DEC8(u4, a0, a1, a2, a3) DEC8(u5, b0, b1, b2, b3)
      DEC8(u6, a0, a1, a2, a3) DEC8(u7, b0, b1, b2, b3)
    }
    for (; e < end; ++e){
      unsigned u = featq[(size_t)csrc[e] * 64 + lane];
      DEC8(u, a0, a1, a2, a3)
    }
    int d = end - start;
    float inv = 1.f / (float)(d > 0 ? d : 1);
    uint2 o; o.x = packbf2((a0 + b0) * inv, (a1 + b1) * inv);
    o.y = packbf2((a2 + b2) * inv, (a3 + b3) * inv);
    *reinterpret_cast<uint2*>(out + (size_t)node * 128 + lane * 2) = o;
  }
}

// out[node][c] = u(already in d_out) + mean(tq fp8 over in-edges) + bl3
__global__ __launch_bounds__(256) void final_k(const unsigned short* __restrict__ tq, float* __restrict__ out,
                        const int* __restrict__ rowp, const int* __restrict__ csrc,
                        const float* __restrict__ bl3){
  const int lane = threadIdx.x & 63;
  const int node0 = __builtin_amdgcn_readfirstlane(blockIdx.x * 4 + (threadIdx.x >> 6));
  const int nw = gridDim.x * 4;
  for (int node = node0; node < NN; node += nw){
    const int start = rowp[node], end = rowp[node + 1];
    float a0 = 0.f, a1 = 0.f, b0 = 0.f, b1 = 0.f;
    int e = start;
    for (; e + 7 < end; e += 8){
      unsigned u0 = tq[(size_t)csrc[e]     * 64 + lane];
      unsigned u1 = tq[(size_t)csrc[e + 1] * 64 + lane];
      unsigned u2 = tq[(size_t)csrc[e + 2] * 64 + lane];
      unsigned u3 = tq[(size_t)csrc[e + 3] * 64 + lane];
      unsigned u4 = tq[(size_t)csrc[e + 4] * 64 + lane];
      unsigned u5 = tq[(size_t)csrc[e + 5] * 64 + lane];
      unsigned u6 = tq[(size_t)csrc[e + 6] * 64 + lane];
      unsigned u7 = tq[(size_t)csrc[e + 7] * 64 + lane];
      a0 += __builtin_amdgcn_cvt_f32_fp8(u0, 0); a1 += __builtin_amdgcn_cvt_f32_fp8(u0, 1);
      b0 += __builtin_amdgcn_cvt_f32_fp8(u1, 0); b1 += __builtin_amdgcn_cvt_f32_fp8(u1, 1);
      a0 += __builtin_amdgcn_cvt_f32_fp8(u2, 0); a1 += __builtin_amdgcn_cvt_f32_fp8(u2, 1);
      b0 += __builtin_amdgcn_cvt_f32_fp8(u3, 0); b1 += __builtin_amdgcn_cvt_f32_fp8(u3, 1);
      a0 += __builtin_amdgcn_cvt_f32_fp8(u4, 0); a1 += __builtin_amdgcn_cvt_f32_fp8(u4, 1);
      b0 += __builtin_amdgcn_cvt_f32_fp8(u5, 0); b1 += __builtin_amdgcn_cvt_f32_fp8(u5, 1);
      a0 += __builtin_amdgcn_cvt_f32_fp8(u6, 0); a1 += __builtin_amdgcn_cvt_f32_fp8(u6, 1);
      b0 += __builtin_amdgcn_cvt_f32_fp8(u7, 0); b1 += __builtin_amdgcn_cvt_f32_fp8(u7, 1);
    }
    for (; e < end; ++e){
      unsigned u = tq[(size_t)csrc[e] * 64 + lane];
      a0 += __builtin_amdgcn_cvt_f32_fp8(u, 0); a1 += __builtin_amdgcn_cvt_f32_fp8(u, 1);
    }
    int d = end - start;
    float inv = 1.f / (float)(d > 0 ? d : 1);
    float2* o = reinterpret_cast<float2*>(out + (size_t)node * 128) + lane;
    float2 v = *o;
    v.x += (a0 + b0) * inv + bl3[lane * 2];
    v.y += (a1 + b1) * inv + bl3[lane * 2 + 1];
    *o = v;
  }
}

// ---------------- GEMM1: A-once-LDS + direct-B + zero-barrier K-loop ----------------
// Block = 64 rows x 256 cols (wave wv owns cols wv*64..+63). A-tile [64][KTOT]
// bf16 loaded ONCE via pre-swizzled-source gload16 (rule #21: involution
// s = ch ^ (row&7); A0/A1 boundary is a multiple of 8 chunks so XOR<=7 never
// crosses it). One vmcnt(0)+barrier, then KTOT/32 unrolled steps: 4 ds_read
// (swizzled slot) + 4 direct-global B fragment loads (B <=256KB, L2-resident,
// each wave-load covers 16 full 64B lines) + 16 MFMA. NO barriers: waves slip
// (this is gemm23-phase-2's measured-fast pattern, ~650 TF effective).
template<int KTOT, int K0>
__global__ __launch_bounds__(256) void gemmA_k(
    const unsigned short* __restrict__ A0, const unsigned short* __restrict__ A1,
    const unsigned short* __restrict__ Bt,
    const float* __restrict__ S, const float* __restrict__ Tt,
    unsigned short* __restrict__ outB, unsigned char* __restrict__ outQ, int M)
{
  constexpr int CB = KTOT * 2;            // bytes per A-tile row
  constexpr int NC = CB / 16;             // 16B chunks per row
  constexpr int NB = K0 / 8;              // A0/A1 boundary chunk (K0*2/16)
  constexpr int RPR = 4096 / CB;          // rows per 256-thread load round
  constexpr int NRND = 64 / RPR;
  __shared__ __align__(16) unsigned char lds[64 * CB];

  const int tid = threadIdx.x;
  const int lane = tid & 63;
  const int wv = tid >> 6;

  const int nwg = gridDim.x;
  const int q = nwg >> 3, r8 = nwg & 7;
  const int xcd = blockIdx.x & 7, idx = blockIdx.x >> 3;
  const int bm = (xcd < r8) ? xcd * (q + 1) + idx : r8 * (q + 1) + (xcd - r8) * q + idx;

  const int l15 = lane & 15, kg = lane >> 4;

  // one-shot A-tile load (linear LDS dest = j*4096 + tid*16; swizzled source)
  {
    const int rr = tid / NC;
    const int ch = tid % NC;
    #pragma unroll
    for (int j = 0; j < NRND; ++j){
      const int row = j * RPR + rr;
      const int s = ch ^ (row & 7);
      int grow = bm * 64 + row; if (grow > M - 1) grow = M - 1;
      const unsigned short* src;
      if (KTOT == K0 || s < NB) src = A0 + (size_t)grow * K0 + s * 8;
      else                      src = A1 + (size_t)grow * (KTOT - K0) + (s - NB) * 8;
      gload16(src, lds + j * 4096 + tid * 16);
    }
  }
  asm volatile("s_waitcnt vmcnt(0)" ::: "memory");
  __builtin_amdgcn_s_barrier();

  f32x4 acc[4][4];
  #pragma unroll
  for (int i = 0; i < 4; ++i)
    #pragma unroll
    for (int j = 0; j < 4; ++j){ acc[i][j][0]=0.f; acc[i][j][1]=0.f; acc[i][j][2]=0.f; acc[i][j][3]=0.f; }

  #pragma unroll
  for (int kt = 0; kt < KTOT / 32; ++kt){
    const int kb = kt * 32;
    bh8 af[4], bf[4];
    #pragma unroll
    for (int mi = 0; mi < 4; ++mi){
      const int row = mi * 16 + l15;
      const int c = kt * 4 + kg;
      af[mi] = *reinterpret_cast<const bh8*>(lds + row * CB + ((c ^ (row & 7)) * 16));
    }
    #pragma unroll
    for (int ni = 0; ni < 4; ++ni){
      const int col = wv * 64 + ni * 16 + l15;
      bf[ni] = *reinterpret_cast<const bh8*>(Bt + (size_t)col * KTOT + kb + kg * 8);
    }
    #pragma unroll
    for (int mi = 0; mi < 4; ++mi)
      #pragma unroll
      for (int ni = 0; ni < 4; ++ni)
        acc[mi][ni] = __builtin_amdgcn_mfma_f32_16x16x32_bf16(af[mi], bf[ni], acc[mi][ni], 0, 0, 0);
  }

  #pragma unroll
  for (int mi = 0; mi < 4; ++mi){
    const int rbase = bm * 64 + mi * 16 + (kg << 2);
    #pragma unroll
    for (int ni = 0; ni < 4; ++ni){
      const int col = wv * 64 + ni * 16 + l15;
      #pragma unroll
      for (int j = 0; j < 4; ++j){
        const int row = rbase + j;
        if (row < M){
          float v = acc[mi][ni][j];
          v = v * S[col] + Tt[col];
          v = v > 0.f ? v : 0.f;
          outB[(size_t)row * 256 + col] = f2bf(v);
          outQ[(size_t)row * 256 + col] = f2fp8(v);
        }
      }
    }
  }
}

// ---------------- FUSED layer-2 + layer-3 GEMM (A-once, direct-B) ----------------
// Phase 1 (K=512): A-tile [64][512] = 64KB loaded once (A0=agg2 k<256,
//   A1=h1 k>=256, boundary chunk 32), direct-B2 from global, SWAPPED
//   mfma(bf, af) so reg-quads hold 4 col-consecutive h2 values; NO barriers.
// Transition: h2 = relu(acc*S+T) -> bf16, packed ds_write into [64][256]
//   swizzled LDS tile OVERLAYING the dead A-tile (total LDS stays 64KB ->
//   2 blocks/CU). Phase 2 (K=256): A from h2 tile, B3 direct; epilogue
//   tq fp8 (cols<128) + outF f32 (cols>=128). h2 never touches global.
__global__ __launch_bounds__(256) void gemm23_k(
    const unsigned short* __restrict__ A0 /*agg2 [NN][256]*/,
    const unsigned short* __restrict__ A1 /*h1   [NN][256]*/,
    const unsigned short* __restrict__ B2 /*B2t [256][512]*/,
    const unsigned short* __restrict__ B3 /*B3t [256][256]*/,
    const float* __restrict__ S, const float* __restrict__ Tt,
    unsigned char* __restrict__ tq, float* __restrict__ outF, int M)
{
  __shared__ __align__(16) unsigned char lds[65536];  // A-tile [64][1024B]; h2 tile overlays [0,32K)
  const int tid = threadIdx.x;
  const int lane = tid & 63;
  const int wv = tid >> 6;

  const int nwg = gridDim.x;
  const int q = nwg >> 3, r8 = nwg & 7;
  const int xcd = blockIdx.x & 7, idx = blockIdx.x >> 3;
  const int bm = (xcd < r8) ? xcd * (q + 1) + idx : r8 * (q + 1) + (xcd - r8) * q + idx;

  const int l15 = lane & 15, kg = lane >> 4;

  // one-shot A-tile load: CB=1024, NC=64, 4 rows/round, 16 rounds; boundary chunk 32
  {
    const int rr = tid >> 6;            // tid / 64
    const int ch = tid & 63;
    #pragma unroll
    for (int j = 0; j < 16; ++j){
      const int row = j * 4 + rr;
      const int s = ch ^ (row & 7);
      int grow = bm * 64 + row; if (grow > M - 1) grow = M - 1;
      const unsigned short* src = (s < 32) ? (A0 + (size_t)grow * 256 + s * 8)
                                           : (A1 + (size_t)grow * 256 + (s - 32) * 8);
      gload16(src, lds + j * 4096 + tid * 16);
    }
  }
  asm volatile("s_waitcnt vmcnt(0)" ::: "memory");
  __builtin_amdgcn_s_barrier();

  f32x4 acc[4][4];
  #pragma unroll
  for (int i = 0; i < 4; ++i)
    #pragma unroll
    for (int j = 0; j < 4; ++j){ acc[i][j][0]=0.f; acc[i][j][1]=0.f; acc[i][j][2]=0.f; acc[i][j][3]=0.f; }

  #pragma unroll
  for (int kt = 0; kt < 16; ++kt){
    const int kb = kt * 32;
    bh8 af[4], bf[4];
    #pragma unroll
    for (int mi = 0; mi < 4; ++mi){
      const int row = mi * 16 + l15;
      const int c = kt * 4 + kg;
      af[mi] = *reinterpret_cast<const bh8*>(lds + row * 1024 + ((c ^ (row & 7)) * 16));
    }
    #pragma unroll
    for (int ni = 0; ni < 4; ++ni){
      const int col = wv * 64 + ni * 16 + l15;
      bf[ni] = *reinterpret_cast<const bh8*>(B2 + (size_t)col * 512 + kb + kg * 8);
    }
    #pragma unroll
    for (int mi = 0; mi < 4; ++mi)
      #pragma unroll
      for (int ni = 0; ni < 4; ++ni)   // SWAPPED: value = h2[m=l15-side][n=reg-side]
        acc[mi][ni] = __builtin_amdgcn_mfma_f32_16x16x32_bf16(bf[ni], af[mi], acc[mi][ni], 0, 0, 0);
  }

  // ---- transition: h2 -> [64][256] bf16 swizzled LDS tile (overlays dead A) ----
  __syncthreads();
  #pragma unroll
  for (int mi = 0; mi < 4; ++mi){
    const int row = mi * 16 + l15;
    #pragma unroll
    for (int ni = 0; ni < 4; ++ni){
      const int c0 = wv * 64 + ni * 16 + kg * 4;
      float v0 = acc[mi][ni][0] * S[c0]     + Tt[c0];     v0 = v0 > 0.f ? v0 : 0.f;
      float v1 = acc[mi][ni][1] * S[c0 + 1] + Tt[c0 + 1]; v1 = v1 > 0.f ? v1 : 0.f;
      float v2 = acc[mi][ni][2] * S[c0 + 2] + Tt[c0 + 2]; v2 = v2 > 0.f ? v2 : 0.f;
      float v3 = acc[mi][ni][3] * S[c0 + 3] + Tt[c0 + 3]; v3 = v3 > 0.f ? v3 : 0.f;
      uint2 w; w.x = packbf2(v0, v1); w.y = packbf2(v2, v3);
      const int chunk = wv * 8 + ni * 2 + (kg >> 1);
      const int byte = row * 512 + ((chunk ^ (row & 7)) * 16) + (kg & 1) * 8;
      *reinterpret_cast<uint2*>(lds + byte) = w;
    }
  }
  __syncthreads();

  // ---- phase 2: out = h2_tile @ B3t^T (K = 256) ----
  f32x4 acc2[4][4];
  #pragma unroll
  for (int i = 0; i < 4; ++i)
    #pragma unroll
    for (int j = 0; j < 4; ++j){ acc2[i][j][0]=0.f; acc2[i][j][1]=0.f; acc2[i][j][2]=0.f; acc2[i][j][3]=0.f; }

  #pragma unroll
  for (int kt = 0; kt < 8; ++kt){
    const int kb = kt * 32;
    bh8 af2[4], bf2[4];
    #pragma unroll
    for (int mi = 0; mi < 4; ++mi){
      const int row = mi * 16 + l15;
      const int chunk = kt * 4 + kg;
      af2[mi] = *reinterpret_cast<const bh8*>(lds + row * 512 + ((chunk ^ (row & 7)) * 16));
    }
    #pragma unroll
    for (int ni = 0; ni < 4; ++ni)
      bf2[ni] = *reinterpret_cast<const bh8*>(B3 + (size_t)(wv * 64 + ni * 16 + l15) * 256 + kb + kg * 8);
    #pragma unroll
    for (int mi = 0; mi < 4; ++mi)
      #pragma unroll
      for (int ni = 0; ni < 4; ++ni)
        acc2[mi][ni] = __builtin_amdgcn_mfma_f32_16x16x32_bf16(af2[mi], bf2[ni], acc2[mi][ni], 0, 0, 0);
  }

  #pragma unroll
  for (int mi = 0; mi < 4; ++mi){
    const int rbase = bm * 64 + mi * 16 + (kg << 2);
    #pragma unroll
    for (int ni = 0; ni < 4; ++ni){
      const int col = wv * 64 + ni * 16 + l15;
      #pragma unroll
      for (int j = 0; j < 4; ++j){
        const int row = rbase + j;
        if (row < M){
          float v = acc2[mi][ni][j];
          if (col < 128) tq[(size_t)row * 128 + col] = f2fp8(v);
          else           outF[(size_t)row * 128 + (col - 128)] = v;
        }
      }
    }
  }
}

// ---------------- launch ----------------
extern "C" void kernel_launch(void* const* d_in, const int* in_sizes, int n_in,
                              void* d_out, int out_size, void* d_ws, size_t ws_size,
                              hipStream_t stream) {
  (void)in_sizes; (void)n_in; (void)out_size; (void)ws_size;
  const float* x   = (const float*)d_in[0];
  const int*   ei  = (const int*)d_in[1];
  const int*   srcv = ei;
  const int*   dstv = ei + NE;
  const float* wl1 = (const float*)d_in[2];
  const float* bl1 = (const float*)d_in[3];
  const float* wr1 = (const float*)d_in[4];
  const float* wl2 = (const float*)d_in[5];
  const float* bl2 = (const float*)d_in[6];
  const float* wr2 = (const float*)d_in[7];
  const float* wl3 = (const float*)d_in[8];
  const float* bl3 = (const float*)d_in[9];
  const float* wr3 = (const float*)d_in[10];
  const float* bn1w = (const float*)d_in[11];
  const float* bn1b = (const float*)d_in[12];
  const float* bn1m = (const float*)d_in[13];
  const float* bn1v = (const float*)d_in[14];
  const float* bn2w = (const float*)d_in[15];
  const float* bn2b = (const float*)d_in[16];
  const float* bn2m = (const float*)d_in[17];
  const float* bn2v = (const float*)d_in[18];

  char* ws = (char*)d_ws;
  size_t off = 0;
  auto alloc = [&](size_t bytes) -> void* {
    void* p = ws + off;
    off += (bytes + 255) & ~(size_t)255;
    return p;
  };
  int* cnt  = (int*)alloc((size_t)NN * 4);
  int* rank = (int*)alloc((size_t)NE * 4);
  int* rowp = (int*)alloc((size_t)(NN + 1) * 4);
  int* csrc = (int*)alloc((size_t)NE * 4);
  int* bsum = (int*)alloc((size_t)NSB * 4);
  unsigned short* B1t = (unsigned short*)alloc(256 * 256 * 2);
  unsigned short* B2t = (unsigned short*)alloc(256 * 512 * 2);
  unsigned short* B3t = (unsigned short*)alloc(256 * 256 * 2);
  float* S1 = (float*)alloc(256 * 4);
  float* T1 = (float*)alloc(256 * 4);
  float* S2 = (float*)alloc(256 * 4);
  float* T2 = (float*)alloc(256 * 4);
  unsigned short* xb   = (unsigned short*)alloc((size_t)NN * 128 * 2); // agg2 lo half after GEMM1
  unsigned short* agg1 = (unsigned short*)alloc((size_t)NN * 128 * 2); // agg2 hi half after GEMM1
  unsigned short* h1   = (unsigned short*)alloc((size_t)NN * 256 * 2);
  unsigned short* h2   = (unsigned short*)alloc((size_t)NN * 256 * 2); // staging region (h2 never materialized)
  // Overlay lifetimes (stream-ordered):
  //   agg2 spans xb+agg1 — both dead after gemm1 reads them.
  //   h1q = h2[0 : NN*256)             : written by gemm1 epilogue, read by
  //     agg256q, dead before gemm23 starts.
  //   xq  = h2[NN*256 : NN*256+NN*128) : written by f2b, read by agg128q, dead after.
  //   tq  = h2[0 : NN*128)             : written by gemm23 phase-2 (h1q dead),
  //     read by final_k. NOT on h1 — gemm23 reads h1 as A1 concurrently!
  unsigned short* agg2 = xb;
  unsigned char*  h1q  = (unsigned char*)h2;
  unsigned*       xq   = (unsigned*)((unsigned char*)h2 + (size_t)NN * 256);
  unsigned char*  tq   = (unsigned char*)h2;
  float* outp = (float*)d_out;

  hipMemsetAsync(cnt, 0, (size_t)NN * 4, stream);
  hist_k<<<(NE + 255) / 256, 256, 0, stream>>>(dstv, cnt, rank);
  scan1_k<<<NSB, 256, 0, stream>>>(cnt, rowp, bsum);
  scan2_k<<<1, 64, 0, stream>>>(bsum);
  scan3_k<<<NSB, 256, 0, stream>>>(rowp, bsum);
  fill_k<<<1024, 256, 0, stream>>>(srcv, dstv, rank, rowp, csrc);
  prep_k<<<1026, 256, 0, stream>>>(wl1, wr1, wl2, wr2, wl3, wr3, bl1, bl2,
                                   bn1w, bn1b, bn1m, bn1v, bn2w, bn2b, bn2m, bn2v,
                                   B1t, B2t, B3t, S1, T1, S2, T2);
  f2b_k<<<(NN * 128 / 4 + 255) / 256, 256, 0, stream>>>((const float4*)x, (uint2*)xb, xq);

  // layer 1: gather fp8 x, then A-once/direct-B GEMM -> h1 bf16 + h1q fp8
  agg128q_k<<<AGG_BLOCKS, 256, 0, stream>>>((const unsigned short*)xq, (unsigned*)agg1, rowp, csrc);
  gemmA_k<256, 128><<<782, 256, 0, stream>>>(agg1, xb, B1t, S1, T1, h1, h1q, NN);
  // layer 2 gather (fp8 h1), then FUSED layer-2+3 GEMM (h2 stays in LDS)
  agg256q_k<<<AGG_BLOCKS, 256, 0, stream>>>((const unsigned*)h1q, (unsigned*)agg2, rowp, csrc);
  gemm23_k<<<782, 256, 0, stream>>>(agg2, h1, B2t, B3t, S2, T2, tq, outp, NN);
  final_k<<<AGG_BLOCKS, 256, 0, stream>>>((const unsigned short*)tq, outp, rowp, csrc, bl3);
}

// Round 15
// 240.841 us; speedup vs baseline: 1.1087x; 1.1087x over previous
//
#include <hip/hip_runtime.h>
#include <hip/hip_bf16.h>

#define NN 50000
#define NE 800000
#define NSB 49   // scan blocks: 49 * 1024 >= NN
#define AGG_BLOCKS 2048

typedef __attribute__((ext_vector_type(8))) short bh8;
typedef __attribute__((ext_vector_type(4))) float f32x4;

static __device__ __forceinline__ unsigned short f2bf(float f){
  unsigned u = __float_as_uint(f);
  unsigned r = (u + 0x7fffu + ((u >> 16) & 1u)) >> 16;
  return (unsigned short)r;
}
static __device__ __forceinline__ float bflo(unsigned u){ return __uint_as_float(u << 16); }
static __device__ __forceinline__ float bfhi(unsigned u){ return __uint_as_float(u & 0xffff0000u); }
static __device__ __forceinline__ unsigned packbf2(float lo, float hi){
  return ((unsigned)f2bf(hi) << 16) | (unsigned)f2bf(lo);
}
static __device__ __forceinline__ unsigned char f2fp8(float v){
  return (unsigned char)(__builtin_amdgcn_cvt_pk_fp8_f32(v, v, 0, false) & 0xff);
}

// async global->LDS, 16B per lane, LDS dest = wave-uniform base + lane*16
static __device__ __forceinline__ void gload16(const void* g, void* l){
  __builtin_amdgcn_global_load_lds(
      (const __attribute__((address_space(1))) unsigned int*)g,
      (__attribute__((address_space(3))) unsigned int*)l, 16, 0, 0);
}

// ---------------- CSR build ----------------
__global__ void hist_k(const int* __restrict__ dstv, int* __restrict__ cnt,
                       int* __restrict__ rank){
  int i = blockIdx.x * 256 + threadIdx.x;
  if (i < NE) rank[i] = atomicAdd(&cnt[dstv[i]], 1);
}

__global__ __launch_bounds__(256) void scan1_k(const int* __restrict__ cnt,
                                               int* __restrict__ rowp,
                                               int* __restrict__ bsum){
  __shared__ int sa[256], sb[256];
  const int t = threadIdx.x, blk = blockIdx.x;
  const int base = blk * 1024 + t * 4;
  int4 v = make_int4(0, 0, 0, 0);
  if (base + 3 < NN) v = *reinterpret_cast<const int4*>(cnt + base);
  else if (base < NN){
    v.x = cnt[base];
    if (base + 1 < NN) v.y = cnt[base + 1];
    if (base + 2 < NN) v.z = cnt[base + 2];
  }
  const int s = v.x + v.y + v.z + v.w;
  sa[t] = s; __syncthreads();
  int* a = sa; int* b = sb;
  for (int off = 1; off < 256; off <<= 1){
    int val = a[t]; if (t >= off) val += a[t - off];
    b[t] = val; __syncthreads();
    int* tmp = a; a = b; b = tmp;
  }
  const int ex = a[t] - s;             // exclusive prefix within block
  if (base < NN){
    rowp[base] = ex;
    if (base + 1 < NN) rowp[base + 1] = ex + v.x;
    if (base + 2 < NN) rowp[base + 2] = ex + v.x + v.y;
    if (base + 3 < NN) rowp[base + 3] = ex + v.x + v.y + v.z;
  }
  if (t == 255) bsum[blk] = a[255];    // block total
}

__global__ void scan2_k(int* __restrict__ bsum){
  __shared__ int s[64];
  const int t = threadIdx.x;
  s[t] = (t < NSB) ? bsum[t] : 0;
  __syncthreads();
  if (t == 0){
    int run = 0;
    for (int i = 0; i < NSB; ++i){ int c = s[i]; s[i] = run; run += c; }
  }
  __syncthreads();
  if (t < NSB) bsum[t] = s[t];
}

__global__ __launch_bounds__(256) void scan3_k(int* __restrict__ rowp,
                                               const int* __restrict__ bsum){
  const int blk = blockIdx.x;
  const int base = blk * 1024 + threadIdx.x * 4;
  const int off = bsum[blk];
  #pragma unroll
  for (int i = 0; i < 4; ++i){
    int idx = base + i;
    if (idx < NN) rowp[idx] += off;
  }
  if (blk == 0 && threadIdx.x == 0) rowp[NN] = NE;
}

// dst-range-partitioned, ATOMIC-FREE fill: csrc[rowp[d]+rank[i]] = srcv[i].
__global__ __launch_bounds__(256) void fill_k(const int* __restrict__ srcv,
                       const int* __restrict__ dstv,
                       const int* __restrict__ rank,
                       const int* __restrict__ rowp, int* __restrict__ csrc){
  const int part  = blockIdx.x & 7;
  const int chunk = blockIdx.x >> 3;           // 0..127
  const int lo = part * (NN / 8);
  const int hi = lo + (NN / 8);                // NN%8==0
  const int base = chunk * (NE / 128);         // NE%128==0
  const int endi = base + (NE / 128);
  for (int i = base + threadIdx.x; i < endi; i += 256){
    int d = dstv[i];
    if (d >= lo && d < hi){
      csrc[rowp[d] + rank[i]] = srcv[i];
    }
  }
}

// ---------------- conversions / weight prep ----------------
// x f32 -> xb bf16 (GEMM self-term) AND xq fp8 (layer-1 gather table)
__global__ void f2b_k(const float4* __restrict__ x, uint2* __restrict__ xb,
                      unsigned* __restrict__ xq){
  int i = blockIdx.x * 256 + threadIdx.x;
  if (i < NN * 128 / 4){
    float4 v = x[i];
    uint2 o; o.x = packbf2(v.x, v.y); o.y = packbf2(v.z, v.w);
    xb[i] = o;
    int w = 0;
    w = __builtin_amdgcn_cvt_pk_fp8_f32(v.x, v.y, w, false);
    w = __builtin_amdgcn_cvt_pk_fp8_f32(v.z, v.w, w, true);
    xq[i] = (unsigned)w;
  }
}

// B1t[n][k] k<128->wl1, else wr1 ; B2t[n][k] k<256->wl2 else wr2 ;
// B3t[n][k] n<128->wl3 col n, else wr3 col n-128 ; plus BN affine S/T.
__global__ void prep_k(const float* __restrict__ wl1, const float* __restrict__ wr1,
                       const float* __restrict__ wl2, const float* __restrict__ wr2,
                       const float* __restrict__ wl3, const float* __restrict__ wr3,
                       const float* __restrict__ bl1, const float* __restrict__ bl2,
                       const float* __restrict__ bn1w, const float* __restrict__ bn1b,
                       const float* __restrict__ bn1m, const float* __restrict__ bn1v,
                       const float* __restrict__ bn2w, const float* __restrict__ bn2b,
                       const float* __restrict__ bn2m, const float* __restrict__ bn2v,
                       unsigned short* __restrict__ B1t, unsigned short* __restrict__ B2t,
                       unsigned short* __restrict__ B3t,
                       float* __restrict__ S1, float* __restrict__ T1,
                       float* __restrict__ S2, float* __restrict__ T2){
  int i = blockIdx.x * 256 + threadIdx.x;
  if (i < 65536){
    int n = i >> 8, k = i & 255;
    float v = (k < 128) ? wl1[k * 256 + n] : wr1[(k - 128) * 256 + n];
    B1t[n * 256 + k] = f2bf(v);
  } else if (i < 65536 + 131072){
    int j = i - 65536; int n = j >> 9, k = j & 511;
    float v = (k < 256) ? wl2[k * 256 + n] : wr2[(k - 256) * 256 + n];
    B2t[n * 512 + k] = f2bf(v);
  } else if (i < 65536 + 131072 + 65536){
    int j = i - (65536 + 131072); int n = j >> 8, k = j & 255;
    float v = (n < 128) ? wl3[k * 128 + n] : wr3[k * 128 + (n - 128)];
    B3t[n * 256 + k] = f2bf(v);
  } else if (i < 65536 + 131072 + 65536 + 512){
    int j = i - (65536 + 131072 + 65536);
    if (j < 256){
      float s = bn1w[j] * rsqrtf(bn1v[j] + 1e-5f);
      S1[j] = s; T1[j] = (bl1[j] - bn1m[j]) * s + bn1b[j];
    } else {
      int c = j - 256;
      float s = bn2w[c] * rsqrtf(bn2v[c] + 1e-5f);
      S2[c] = s; T2[c] = (bl2[c] - bn2m[c]) * s + bn2b[c];
    }
  }
}

// ---------------- mean aggregation (gather via CSR) ----------------
__global__ __launch_bounds__(256) void agg128q_k(const unsigned short* __restrict__ featq,
                         unsigned* __restrict__ out,
                         const int* __restrict__ rowp, const int* __restrict__ csrc){
  const int lane = threadIdx.x & 63;
  const int node0 = __builtin_amdgcn_readfirstlane(blockIdx.x * 4 + (threadIdx.x >> 6));
  const int nw = gridDim.x * 4;
  for (int node = node0; node < NN; node += nw){
    const int start = rowp[node], end = rowp[node + 1];
    float a0 = 0.f, a1 = 0.f, b0 = 0.f, b1 = 0.f;
    int e = start;
    for (; e + 7 < end; e += 8){
      unsigned u0 = featq[(size_t)csrc[e]     * 64 + lane];
      unsigned u1 = featq[(size_t)csrc[e + 1] * 64 + lane];
      unsigned u2 = featq[(size_t)csrc[e + 2] * 64 + lane];
      unsigned u3 = featq[(size_t)csrc[e + 3] * 64 + lane];
      unsigned u4 = featq[(size_t)csrc[e + 4] * 64 + lane];
      unsigned u5 = featq[(size_t)csrc[e + 5] * 64 + lane];
      unsigned u6 = featq[(size_t)csrc[e + 6] * 64 + lane];
      unsigned u7 = featq[(size_t)csrc[e + 7] * 64 + lane];
      a0 += __builtin_amdgcn_cvt_f32_fp8(u0, 0); a1 += __builtin_amdgcn_cvt_f32_fp8(u0, 1);
      b0 += __builtin_amdgcn_cvt_f32_fp8(u1, 0); b1 += __builtin_amdgcn_cvt_f32_fp8(u1, 1);
      a0 += __builtin_amdgcn_cvt_f32_fp8(u2, 0); a1 += __builtin_amdgcn_cvt_f32_fp8(u2, 1);
      b0 += __builtin_amdgcn_cvt_f32_fp8(u3, 0); b1 += __builtin_amdgcn_cvt_f32_fp8(u3, 1);
      a0 += __builtin_amdgcn_cvt_f32_fp8(u4, 0); a1 += __builtin_amdgcn_cvt_f32_fp8(u4, 1);
      b0 += __builtin_amdgcn_cvt_f32_fp8(u5, 0); b1 += __builtin_amdgcn_cvt_f32_fp8(u5, 1);
      a0 += __builtin_amdgcn_cvt_f32_fp8(u6, 0); a1 += __builtin_amdgcn_cvt_f32_fp8(u6, 1);
      b0 += __builtin_amdgcn_cvt_f32_fp8(u7, 0); b1 += __builtin_amdgcn_cvt_f32_fp8(u7, 1);
    }
    for (; e < end; ++e){
      unsigned u = featq[(size_t)csrc[e] * 64 + lane];
      a0 += __builtin_amdgcn_cvt_f32_fp8(u, 0); a1 += __builtin_amdgcn_cvt_f32_fp8(u, 1);
    }
    int d = end - start;
    float inv = 1.f / (float)(d > 0 ? d : 1);
    out[(size_t)node * 64 + lane] = packbf2((a0 + b0) * inv, (a1 + b1) * inv);
  }
}

#define DEC8(u, x0, x1, x2, x3) { \
  x0 += __builtin_amdgcn_cvt_f32_fp8((u), 0); \
  x1 += __builtin_amdgcn_cvt_f32_fp8((u), 1); \
  x2 += __builtin_amdgcn_cvt_f32_fp8((u), 2); \
  x3 += __builtin_amdgcn_cvt_f32_fp8((u), 3); }

__global__ __launch_bounds__(256) void agg256q_k(const unsigned* __restrict__ featq, unsigned* __restrict__ out,
                         const int* __restrict__ rowp, const int* __restrict__ csrc){
  const int lane = threadIdx.x & 63;
  const int node0 = __builtin_amdgcn_readfirstlane(blockIdx.x * 4 + (threadIdx.x >> 6));
  const int nw = gridDim.x * 4;
  for (int node = node0; node < NN; node += nw){
    const int start = rowp[node], end = rowp[node + 1];
    float a0 = 0.f, a1 = 0.f, a2 = 0.f, a3 = 0.f;
    float b0 = 0.f, b1 = 0.f, b2 = 0.f, b3 = 0.f;
    int e = start;
    for (; e + 7 < end; e += 8){
      unsigned u0 = featq[(size_t)csrc[e]     * 64 + lane];
      unsigned u1 = featq[(size_t)csrc[e + 1] * 64 + lane];
      unsigned u2 = featq[(size_t)csrc[e + 2] * 64 + lane];
      unsigned u3 = featq[(size_t)csrc[e + 3] * 64 + lane];
      unsigned u4 = featq[(size_t)csrc[e + 4] * 64 + lane];
      unsigned u5 = featq[(size_t)csrc[e + 5] * 64 + lane];
      unsigned u6 = featq[(size_t)csrc[e + 6] * 64 + lane];
      unsigned u7 = featq[(size_t)csrc[e + 7] * 64 + lane];
      DEC8(u0, a0, a1, a2, a3) DEC8(u1, b0, b1, b2, b3)
      DEC8(u2, a0, a1, a2, a3) DEC8(u3, b0, b1, b2, b3)
      DEC8(u4, a0, a1, a2, a3) DEC8(u5, b0, b1, b2, b3)
      DEC8(u6, a0, a1, a2, a3) DEC8(u7, b0, b1, b2, b3)
    }
    for (; e < end; ++e){
      unsigned u = featq[(size_t)csrc[e] * 64 + lane];
      DEC8(u, a0, a1, a2, a3)
    }
    int d = end - start;
    float inv = 1.f / (float)(d > 0 ? d : 1);
    uint2 o; o.x = packbf2((a0 + b0) * inv, (a1 + b1) * inv);
    o.y = packbf2((a2 + b2) * inv, (a3 + b3) * inv);
    *reinterpret_cast<uint2*>(out + (size_t)node * 128 + lane * 2) = o;
  }
}

// out[node][c] = ub(bf16) + mean(tq fp8 over in-edges) + bl3  (write-only on out)
__global__ __launch_bounds__(256) void final_k(const unsigned short* __restrict__ tq,
                        const unsigned* __restrict__ ub, float* __restrict__ out,
                        const int* __restrict__ rowp, const int* __restrict__ csrc,
                        const float* __restrict__ bl3){
  const int lane = threadIdx.x & 63;
  const int node0 = __builtin_amdgcn_readfirstlane(blockIdx.x * 4 + (threadIdx.x >> 6));
  const int nw = gridDim.x * 4;
  for (int node = node0; node < NN; node += nw){
    const int start = rowp[node], end = rowp[node + 1];
    float a0 = 0.f, a1 = 0.f, b0 = 0.f, b1 = 0.f;
    int e = start;
    for (; e + 7 < end; e += 8){
      unsigned u0 = tq[(size_t)csrc[e]     * 64 + lane];
      unsigned u1 = tq[(size_t)csrc[e + 1] * 64 + lane];
      unsigned u2 = tq[(size_t)csrc[e + 2] * 64 + lane];
      unsigned u3 = tq[(size_t)csrc[e + 3] * 64 + lane];
      unsigned u4 = tq[(size_t)csrc[e + 4] * 64 + lane];
      unsigned u5 = tq[(size_t)csrc[e + 5] * 64 + lane];
      unsigned u6 = tq[(size_t)csrc[e + 6] * 64 + lane];
      unsigned u7 = tq[(size_t)csrc[e + 7] * 64 + lane];
      a0 += __builtin_amdgcn_cvt_f32_fp8(u0, 0); a1 += __builtin_amdgcn_cvt_f32_fp8(u0, 1);
      b0 += __builtin_amdgcn_cvt_f32_fp8(u1, 0); b1 += __builtin_amdgcn_cvt_f32_fp8(u1, 1);
      a0 += __builtin_amdgcn_cvt_f32_fp8(u2, 0); a1 += __builtin_amdgcn_cvt_f32_fp8(u2, 1);
      b0 += __builtin_amdgcn_cvt_f32_fp8(u3, 0); b1 += __builtin_amdgcn_cvt_f32_fp8(u3, 1);
      a0 += __builtin_amdgcn_cvt_f32_fp8(u4, 0); a1 += __builtin_amdgcn_cvt_f32_fp8(u4, 1);
      b0 += __builtin_amdgcn_cvt_f32_fp8(u5, 0); b1 += __builtin_amdgcn_cvt_f32_fp8(u5, 1);
      a0 += __builtin_amdgcn_cvt_f32_fp8(u6, 0); a1 += __builtin_amdgcn_cvt_f32_fp8(u6, 1);
      b0 += __builtin_amdgcn_cvt_f32_fp8(u7, 0); b1 += __builtin_amdgcn_cvt_f32_fp8(u7, 1);
    }
    for (; e < end; ++e){
      unsigned u = tq[(size_t)csrc[e] * 64 + lane];
      a0 += __builtin_amdgcn_cvt_f32_fp8(u, 0); a1 += __builtin_amdgcn_cvt_f32_fp8(u, 1);
    }
    int d = end - start;
    float inv = 1.f / (float)(d > 0 ? d : 1);
    unsigned uw = ub[(size_t)node * 64 + lane];
    float2 v;
    v.x = bflo(uw) + (a0 + b0) * inv + bl3[lane * 2];
    v.y = bfhi(uw) + (a1 + b1) * inv + bl3[lane * 2 + 1];
    *(reinterpret_cast<float2*>(out + (size_t)node * 128) + lane) = v;
  }
}

// ---------------- GEMM1 (round-8 structure, best measured) ----------------
template<int KTOT, int K0, int MODE>
__global__ __launch_bounds__(256) void gemm_k(
    const unsigned short* __restrict__ A0, const unsigned short* __restrict__ A1,
    const unsigned short* __restrict__ Bt,
    const float* __restrict__ S, const float* __restrict__ Tt,
    unsigned short* __restrict__ outB, unsigned char* __restrict__ outQ,
    float* __restrict__ outF, int M)
{
  __shared__ __align__(16) unsigned char lds[49152];   // 3 bufs x (A 8K | B 8K)
  const int tid = threadIdx.x;
  const int lane = tid & 63;
  const int wv = tid >> 6;
  const int wm = wv >> 1, wn = wv & 1;

  const int nwg = gridDim.x;
  const int q = nwg >> 3, r8 = nwg & 7;
  const int xcd = blockIdx.x & 7, idx = blockIdx.x >> 3;
  const int wg = (xcd < r8) ? xcd * (q + 1) + idx : r8 * (q + 1) + (xcd - r8) * q + idx;
  const int bm = wg >> 1, bn = wg & 1;

  const int rr0 = tid >> 2,         g0 = (tid & 3) ^ ((tid >> 3) & 3);
  const int rr1 = (tid + 256) >> 2, g1 = ((tid + 256) & 3) ^ (((tid + 256) >> 3) & 3);
  int growA0 = bm * 128 + rr0; if (growA0 > M - 1) growA0 = M - 1;
  int growA1 = bm * 128 + rr1; if (growA1 > M - 1) growA1 = M - 1;
  const size_t browA0 = (size_t)(bn * 128 + rr0) * KTOT;
  const size_t browA1 = (size_t)(bn * 128 + rr1) * KTOT;

  const int l15 = lane & 15, kg = lane >> 4;
  const int slot = (kg ^ ((l15 >> 1) & 3)) * 16;

  constexpr int NT = KTOT / 32;

  auto STAGE = [&](int buf, int kt){
    const int kb = kt * 32;
    const unsigned short* Ap; int pitch, kk;
    if (KTOT == K0 || kb < K0){ Ap = A0; pitch = K0; kk = kb; }
    else { Ap = A1; pitch = KTOT - K0; kk = kb - K0; }
    unsigned char* base = lds + buf * 16384;
    gload16(Ap + (size_t)growA0 * pitch + kk + g0 * 8, base + tid * 16);
    gload16(Ap + (size_t)growA1 * pitch + kk + g1 * 8, base + 4096 + tid * 16);
    gload16(Bt + browA0 + kb + g0 * 8, base + 8192 + tid * 16);
    gload16(Bt + browA1 + kb + g1 * 8, base + 12288 + tid * 16);
  };

  f32x4 acc[4][4];
  #pragma unroll
  for (int i = 0; i < 4; ++i)
    #pragma unroll
    for (int j = 0; j < 4; ++j){ acc[i][j][0]=0.f; acc[i][j][1]=0.f; acc[i][j][2]=0.f; acc[i][j][3]=0.f; }

  STAGE(0, 0);
  if (NT > 1) STAGE(1, 1);

  int rb = 0, sb = 2;
  for (int kt = 0; kt < NT; ++kt){
    if (kt < NT - 1) asm volatile("s_waitcnt vmcnt(4)" ::: "memory");
    else             asm volatile("s_waitcnt vmcnt(0)" ::: "memory");
    __builtin_amdgcn_s_barrier();
    __builtin_amdgcn_sched_barrier(0);

    if (kt + 2 < NT){ STAGE(sb, kt + 2); sb = (sb == 2) ? 0 : sb + 1; }

    unsigned char* base = lds + rb * 16384;
    rb = (rb == 2) ? 0 : rb + 1;

    bh8 af[4], bf[4];
    #pragma unroll
    for (int mi = 0; mi < 4; ++mi){
      int rA = wm * 64 + mi * 16 + l15;
      af[mi] = *reinterpret_cast<const bh8*>(base + rA * 64 + slot);
    }
    #pragma unroll
    for (int ni = 0; ni < 4; ++ni){
      int rB = wn * 64 + ni * 16 + l15;
      bf[ni] = *reinterpret_cast<const bh8*>(base + 8192 + rB * 64 + slot);
    }
    __builtin_amdgcn_s_setprio(1);
    #pragma unroll
    for (int mi = 0; mi < 4; ++mi)
      #pragma unroll
      for (int ni = 0; ni < 4; ++ni)
        acc[mi][ni] = __builtin_amdgcn_mfma_f32_16x16x32_bf16(af[mi], bf[ni], acc[mi][ni], 0, 0, 0);
    __builtin_amdgcn_s_setprio(0);
  }

  #pragma unroll
  for (int mi = 0; mi < 4; ++mi){
    int rbase = bm * 128 + wm * 64 + mi * 16 + ((lane >> 4) << 2);
    #pragma unroll
    for (int ni = 0; ni < 4; ++ni){
      int col = bn * 128 + wn * 64 + ni * 16 + (lane & 15);
      #pragma unroll
      for (int j = 0; j < 4; ++j){
        int row = rbase + j;
        if (row < M){
          float v = acc[mi][ni][j];
          if (MODE == 0){
            v = v * S[col] + Tt[col];
            v = v > 0.f ? v : 0.f;
            outB[(size_t)row * 256 + col] = f2bf(v);
            if (outQ) outQ[(size_t)row * 256 + col] = f2fp8(v);
          } else {
            if (col < 128) outQ[(size_t)row * 128 + col] = f2fp8(v);
            else           outF[(size_t)row * 128 + (col - 128)] = v;
          }
        }
      }
    }
  }
}

// ---------------- FUSED layer-2 + layer-3 GEMM (round-13 structure) ----------------
// Phase 1 (K=512, NT=16): 3-buffer counted-vmcnt(5) staged pipeline; SWAPPED
//   mfma(bf, af) so reg-quads hold 4 col-consecutive h2 values -> packed
//   ds_write into [64][256] XOR-swizzled LDS tile (chunk ^ (row&7)).
// Phase 2 (K=256): A from LDS h2 tile, B3 direct from global (L2-resident).
// Epilogue: tq fp8 (cols<128) + ub bf16 (cols>=128) — u never touches f32 global.
__global__ __launch_bounds__(256) void gemm23_k(
    const unsigned short* __restrict__ A0 /*agg2 [NN][256]*/,
    const unsigned short* __restrict__ A1 /*h1   [NN][256]*/,
    const unsigned short* __restrict__ B2 /*B2t [256][512]*/,
    const unsigned short* __restrict__ B3 /*B3t [256][256]*/,
    const float* __restrict__ S, const float* __restrict__ Tt,
    unsigned char* __restrict__ tq, unsigned short* __restrict__ ub, int M)
{
  __shared__ __align__(16) unsigned char lds[61440];  // 3 bufs x 20KB; h2 tile 32KB overlays bufs 0-1
  const int tid = threadIdx.x;
  const int lane = tid & 63;
  const int wv = tid >> 6;                 // wave owns cols wv*64..wv*64+63

  const int nwg = gridDim.x;
  const int q = nwg >> 3, r8 = nwg & 7;
  const int xcd = blockIdx.x & 7, idx = blockIdx.x >> 3;
  const int bm = (xcd < r8) ? xcd * (q + 1) + idx : r8 * (q + 1) + (xcd - r8) * q + idx;

  const int l15 = lane & 15, kg = lane >> 4;
  const int slot = (kg ^ ((l15 >> 1) & 3)) * 16;
  const int rr = tid >> 2;                              // 0..63
  const int g  = (tid & 3) ^ ((tid >> 3) & 3);          // swizzled source chunk
  int grow = bm * 64 + rr; if (grow > M - 1) grow = M - 1;

  auto STAGE = [&](int buf, int kt){
    const int kb = kt * 32;
    const unsigned short* Ap = (kb < 256) ? A0 : A1;
    const int kk = (kb < 256) ? kb : kb - 256;
    unsigned char* base = lds + buf * 20480;
    gload16(Ap + (size_t)grow * 256 + kk + g * 8, base + tid * 16);              // A 4KB
    gload16(B2 + (size_t)(rr      ) * 512 + kb + g * 8, base +  4096 + tid * 16); // B 16KB
    gload16(B2 + (size_t)(rr +  64) * 512 + kb + g * 8, base +  8192 + tid * 16);
    gload16(B2 + (size_t)(rr + 128) * 512 + kb + g * 8, base + 12288 + tid * 16);
    gload16(B2 + (size_t)(rr + 192) * 512 + kb + g * 8, base + 16384 + tid * 16);
  };

  f32x4 acc[4][4];
  #pragma unroll
  for (int i = 0; i < 4; ++i)
    #pragma unroll
    for (int j = 0; j < 4; ++j){ acc[i][j][0]=0.f; acc[i][j][1]=0.f; acc[i][j][2]=0.f; acc[i][j][3]=0.f; }

  STAGE(0, 0);
  STAGE(1, 1);

  int rb = 0, sb = 2;
  #pragma unroll 1
  for (int kt = 0; kt < 16; ++kt){
    if (kt < 15) asm volatile("s_waitcnt vmcnt(5)" ::: "memory");
    else         asm volatile("s_waitcnt vmcnt(0)" ::: "memory");
    __builtin_amdgcn_s_barrier();
    __builtin_amdgcn_sched_barrier(0);

    if (kt + 2 < 16){ STAGE(sb, kt + 2); sb = (sb == 2) ? 0 : sb + 1; }

    unsigned char* base = lds + rb * 20480;
    rb = (rb == 2) ? 0 : rb + 1;

    bh8 af[4], bf[4];
    #pragma unroll
    for (int mi = 0; mi < 4; ++mi)
      af[mi] = *reinterpret_cast<const bh8*>(base + (mi * 16 + l15) * 64 + slot);
    #pragma unroll
    for (int ni = 0; ni < 4; ++ni)
      bf[ni] = *reinterpret_cast<const bh8*>(base + 4096 + (wv * 64 + ni * 16 + l15) * 64 + slot);

    __builtin_amdgcn_s_setprio(1);
    #pragma unroll
    for (int mi = 0; mi < 4; ++mi)
      #pragma unroll
      for (int ni = 0; ni < 4; ++ni)   // SWAPPED operands: value = h2[m=l15-side][n=reg-side]
        acc[mi][ni] = __builtin_amdgcn_mfma_f32_16x16x32_bf16(bf[ni], af[mi], acc[mi][ni], 0, 0, 0);
    __builtin_amdgcn_s_setprio(0);
  }

  // ---- phase transition: h2 tile -> LDS [64 rows][256 cols] bf16, swizzled ----
  __syncthreads();
  #pragma unroll
  for (int mi = 0; mi < 4; ++mi){
    const int row = mi * 16 + l15;
    #pragma unroll
    for (int ni = 0; ni < 4; ++ni){
      const int c0 = wv * 64 + ni * 16 + kg * 4;    // first of 4 consecutive cols
      float v0 = acc[mi][ni][0] * S[c0]     + Tt[c0];     v0 = v0 > 0.f ? v0 : 0.f;
      float v1 = acc[mi][ni][1] * S[c0 + 1] + Tt[c0 + 1]; v1 = v1 > 0.f ? v1 : 0.f;
      float v2 = acc[mi][ni][2] * S[c0 + 2] + Tt[c0 + 2]; v2 = v2 > 0.f ? v2 : 0.f;
      float v3 = acc[mi][ni][3] * S[c0 + 3] + Tt[c0 + 3]; v3 = v3 > 0.f ? v3 : 0.f;
      uint2 w; w.x = packbf2(v0, v1); w.y = packbf2(v2, v3);
      const int chunk = wv * 8 + ni * 2 + (kg >> 1);      // 16B chunk index 0..31
      const int byte = row * 512 + ((chunk ^ (row & 7)) * 16) + (kg & 1) * 8;
      *reinterpret_cast<uint2*>(lds + byte) = w;
    }
  }
  __syncthreads();

  // ---- phase 2: out = h2_tile @ B3t^T (K = 256) ----
  f32x4 acc2[4][4];
  #pragma unroll
  for (int i = 0; i < 4; ++i)
    #pragma unroll
    for (int j = 0; j < 4; ++j){ acc2[i][j][0]=0.f; acc2[i][j][1]=0.f; acc2[i][j][2]=0.f; acc2[i][j][3]=0.f; }

  #pragma unroll 1
  for (int kt = 0; kt < 8; ++kt){
    const int kb = kt * 32;
    bh8 af2[4], bf2[4];
    #pragma unroll
    for (int mi = 0; mi < 4; ++mi){
      const int row = mi * 16 + l15;
      const int chunk = kt * 4 + kg;
      af2[mi] = *reinterpret_cast<const bh8*>(lds + row * 512 + ((chunk ^ (row & 7)) * 16));
    }
    #pragma unroll
    for (int ni = 0; ni < 4; ++ni)
      bf2[ni] = *reinterpret_cast<const bh8*>(B3 + (size_t)(wv * 64 + ni * 16 + l15) * 256 + kb + kg * 8);
    __builtin_amdgcn_s_setprio(1);
    #pragma unroll
    for (int mi = 0; mi < 4; ++mi)
      #pragma unroll
      for (int ni = 0; ni < 4; ++ni)
        acc2[mi][ni] = __builtin_amdgcn_mfma_f32_16x16x32_bf16(af2[mi], bf2[ni], acc2[mi][ni], 0, 0, 0);
    __builtin_amdgcn_s_setprio(0);
  }

  #pragma unroll
  for (int mi = 0; mi < 4; ++mi){
    const int rbase = bm * 64 + mi * 16 + (kg << 2);
    #pragma unroll
    for (int ni = 0; ni < 4; ++ni){
      const int col = wv * 64 + ni * 16 + l15;
      #pragma unroll
      for (int j = 0; j < 4; ++j){
        const int row = rbase + j;
        if (row < M){
          float v = acc2[mi][ni][j];
          if (col < 128) tq[(size_t)row * 128 + col] = f2fp8(v);
          else           ub[(size_t)row * 128 + (col - 128)] = f2bf(v);
        }
      }
    }
  }
}

// ---------------- launch ----------------
extern "C" void kernel_launch(void* const* d_in, const int* in_sizes, int n_in,
                              void* d_out, int out_size, void* d_ws, size_t ws_size,
                              hipStream_t stream) {
  (void)in_sizes; (void)n_in; (void)out_size; (void)ws_size;
  const float* x   = (const float*)d_in[0];
  const int*   ei  = (const int*)d_in[1];
  const int*   srcv = ei;
  const int*   dstv = ei + NE;
  const float* wl1 = (const float*)d_in[2];
  const float* bl1 = (const float*)d_in[3];
  const float* wr1 = (const float*)d_in[4];
  const float* wl2 = (const float*)d_in[5];
  const float* bl2 = (const float*)d_in[6];
  const float* wr2 = (const float*)d_in[7];
  const float* wl3 = (const float*)d_in[8];
  const float* bl3 = (const float*)d_in[9];
  const float* wr3 = (const float*)d_in[10];
  const float* bn1w = (const float*)d_in[11];
  const float* bn1b = (const float*)d_in[12];
  const float* bn1m = (const float*)d_in[13];
  const float* bn1v = (const float*)d_in[14];
  const float* bn2w = (const float*)d_in[15];
  const float* bn2b = (const float*)d_in[16];
  const float* bn2m = (const float*)d_in[17];
  const float* bn2v = (const float*)d_in[18];

  char* ws = (char*)d_ws;
  size_t off = 0;
  auto alloc = [&](size_t bytes) -> void* {
    void* p = ws + off;
    off += (bytes + 255) & ~(size_t)255;
    return p;
  };
  int* cnt  = (int*)alloc((size_t)NN * 4);
  int* rank = (int*)alloc((size_t)NE * 4);
  int* rowp = (int*)alloc((size_t)(NN + 1) * 4);
  int* csrc = (int*)alloc((size_t)NE * 4);
  int* bsum = (int*)alloc((size_t)NSB * 4);
  unsigned short* B1t = (unsigned short*)alloc(256 * 256 * 2);
  unsigned short* B2t = (unsigned short*)alloc(256 * 512 * 2);
  unsigned short* B3t = (unsigned short*)alloc(256 * 256 * 2);
  float* S1 = (float*)alloc(256 * 4);
  float* T1 = (float*)alloc(256 * 4);
  float* S2 = (float*)alloc(256 * 4);
  float* T2 = (float*)alloc(256 * 4);
  unsigned short* xb   = (unsigned short*)alloc((size_t)NN * 128 * 2); // agg2 lo half after GEMM1
  unsigned short* agg1 = (unsigned short*)alloc((size_t)NN * 128 * 2); // agg2 hi half after GEMM1
  unsigned short* h1   = (unsigned short*)alloc((size_t)NN * 256 * 2);
  unsigned short* h2   = (unsigned short*)alloc((size_t)NN * 256 * 2); // staging region (h2 never materialized)
  // Overlay lifetimes (stream-ordered):
  //   agg2 spans xb+agg1 — both dead after gemm1 reads them.
  //   h1q = h2 bytes [0 : NN*256)          : written by gemm1 epilogue, read by
  //     agg256q, dead before gemm23 starts.
  //   xq  = h2 bytes [NN*256 : NN*256+NN*128*? ) fp8 x (6.4MB): written by f2b,
  //     read by agg128q, dead after.
  //   tq  = h2 bytes [0 : NN*128)          : gemm23 phase-2 out, read by final.
  //   ub  = h2 bytes [NN*256 : NN*256 + NN*128*2) bf16 u (12.8MB): gemm23
  //     phase-2 out, read by final. Overlays dead xq region; disjoint from tq.
  //   NONE of tq/ub on h1 — gemm23 reads h1 as A1 concurrently!
  unsigned short* agg2 = xb;
  unsigned char*  h1q  = (unsigned char*)h2;
  unsigned*       xq   = (unsigned*)((unsigned char*)h2 + (size_t)NN * 256);
  unsigned char*  tq   = (unsigned char*)h2;
  unsigned short* ub   = (unsigned short*)((unsigned char*)h2 + (size_t)NN * 256);
  float* outp = (float*)d_out;

  hipMemsetAsync(cnt, 0, (size_t)NN * 4, stream);
  hist_k<<<(NE + 255) / 256, 256, 0, stream>>>(dstv, cnt, rank);
  scan1_k<<<NSB, 256, 0, stream>>>(cnt, rowp, bsum);
  scan2_k<<<1, 64, 0, stream>>>(bsum);
  scan3_k<<<NSB, 256, 0, stream>>>(rowp, bsum);
  fill_k<<<1024, 256, 0, stream>>>(srcv, dstv, rank, rowp, csrc);
  prep_k<<<1026, 256, 0, stream>>>(wl1, wr1, wl2, wr2, wl3, wr3, bl1, bl2,
                                   bn1w, bn1b, bn1m, bn1v, bn2w, bn2b, bn2m, bn2v,
                                   B1t, B2t, B3t, S1, T1, S2, T2);
  f2b_k<<<(NN * 128 / 4 + 255) / 256, 256, 0, stream>>>((const float4*)x, (uint2*)xb, xq);

  // layer 1: gather fp8 x, GEMM writes h1 bf16 + h1q fp8 (fused conversion)
  agg128q_k<<<AGG_BLOCKS, 256, 0, stream>>>((const unsigned short*)xq, (unsigned*)agg1, rowp, csrc);
  gemm_k<256, 128, 0><<<782, 256, 0, stream>>>(agg1, xb, B1t, S1, T1, h1, h1q, nullptr, NN);
  // layer 2 gather (fp8 h1), then FUSED layer-2+3 GEMM (h2 stays in LDS)
  agg256q_k<<<AGG_BLOCKS, 256, 0, stream>>>((const unsigned*)h1q, (unsigned*)agg2, rowp, csrc);
  gemm23_k<<<782, 256, 0, stream>>>(agg2, h1, B2t, B3t, S2, T2, tq, ub, NN);
  final_k<<<AGG_BLOCKS, 256, 0, stream>>>((const unsigned short*)tq, (const unsigned*)ub, outp, rowp, csrc, bl3);
}

// Round 16
// 222.881 us; speedup vs baseline: 1.1980x; 1.0806x over previous
//
#include <hip/hip_runtime.h>
#include <hip/hip_bf16.h>

#define NN 50000
#define NE 800000
#define AGG_BLOCKS 2048

typedef __attribute__((ext_vector_type(8))) short bh8;
typedef __attribute__((ext_vector_type(4))) float f32x4;

static __device__ __forceinline__ unsigned short f2bf(float f){
  unsigned u = __float_as_uint(f);
  unsigned r = (u + 0x7fffu + ((u >> 16) & 1u)) >> 16;
  return (unsigned short)r;
}
static __device__ __forceinline__ float bflo(unsigned u){ return __uint_as_float(u << 16); }
static __device__ __forceinline__ float bfhi(unsigned u){ return __uint_as_float(u & 0xffff0000u); }
static __device__ __forceinline__ unsigned packbf2(float lo, float hi){
  return ((unsigned)f2bf(hi) << 16) | (unsigned)f2bf(lo);
}
static __device__ __forceinline__ unsigned char f2fp8(float v){
  return (unsigned char)(__builtin_amdgcn_cvt_pk_fp8_f32(v, v, 0, false) & 0xff);
}

// async global->LDS, 16B per lane, LDS dest = wave-uniform base + lane*16
static __device__ __forceinline__ void gload16(const void* g, void* l){
  __builtin_amdgcn_global_load_lds(
      (const __attribute__((address_space(1))) unsigned int*)g,
      (__attribute__((address_space(3))) unsigned int*)l, 16, 0, 0);
}

// ---------------- fused pre-chain: CSR build + weight prep + x convert ----------------
// blocks [0,1024): single-pass fixed-slot CSR build. Edge order within a node
//   is irrelevant (mean aggregation), so each edge grabs slot p=atomicAdd(cnt[d])
//   in cslot[d*64+p]. Degrees ~Poisson(16): P(any deg>64) ~ 1e-14; p<64 guard
//   drops the (never-occurring) overflow instead of corrupting. dst-range x8
//   partitioning keeps atomics + the 1.6MB write window XCD-L2-local.
// blocks [1024,2050): weight prep (B1t/B2t/B3t transposes + BN affine S/T).
// blocks [2050,8300): x f32 -> xb bf16 + xq fp8.
// All three groups are independent -> they overlap inside one dispatch.
__global__ __launch_bounds__(256) void pre_k(
    const int* __restrict__ srcv, const int* __restrict__ dstv,
    int* __restrict__ cnt, int* __restrict__ cslot,
    const float4* __restrict__ x, uint2* __restrict__ xb, unsigned* __restrict__ xq,
    const float* __restrict__ wl1, const float* __restrict__ wr1,
    const float* __restrict__ wl2, const float* __restrict__ wr2,
    const float* __restrict__ wl3, const float* __restrict__ wr3,
    const float* __restrict__ bl1, const float* __restrict__ bl2,
    const float* __restrict__ bn1w, const float* __restrict__ bn1b,
    const float* __restrict__ bn1m, const float* __restrict__ bn1v,
    const float* __restrict__ bn2w, const float* __restrict__ bn2b,
    const float* __restrict__ bn2m, const float* __restrict__ bn2v,
    unsigned short* __restrict__ B1t, unsigned short* __restrict__ B2t,
    unsigned short* __restrict__ B3t,
    float* __restrict__ S1, float* __restrict__ T1,
    float* __restrict__ S2, float* __restrict__ T2)
{
  const int blk = blockIdx.x;
  if (blk < 1024){
    // ---- CSR build ----
    const int part  = blk & 7;
    const int chunk = blk >> 3;                // 0..127
    const int lo = part * (NN / 8);
    const int hi = lo + (NN / 8);
    const int base = chunk * (NE / 128);
    const int endi = base + (NE / 128);
    for (int i = base + threadIdx.x; i < endi; i += 256){
      int d = dstv[i];
      if (d >= lo && d < hi){
        int p = atomicAdd(&cnt[d], 1);
        if (p < 64) cslot[(d << 6) + p] = srcv[i];
      }
    }
  } else if (blk < 2050){
    // ---- weight prep ----
    int i = (blk - 1024) * 256 + threadIdx.x;
    if (i < 65536){
      int n = i >> 8, k = i & 255;
      float v = (k < 128) ? wl1[k * 256 + n] : wr1[(k - 128) * 256 + n];
      B1t[n * 256 + k] = f2bf(v);
    } else if (i < 65536 + 131072){
      int j = i - 65536; int n = j >> 9, k = j & 511;
      float v = (k < 256) ? wl2[k * 256 + n] : wr2[(k - 256) * 256 + n];
      B2t[n * 512 + k] = f2bf(v);
    } else if (i < 65536 + 131072 + 65536){
      int j = i - (65536 + 131072); int n = j >> 8, k = j & 255;
      float v = (n < 128) ? wl3[k * 128 + n] : wr3[k * 128 + (n - 128)];
      B3t[n * 256 + k] = f2bf(v);
    } else if (i < 65536 + 131072 + 65536 + 512){
      int j = i - (65536 + 131072 + 65536);
      if (j < 256){
        float s = bn1w[j] * rsqrtf(bn1v[j] + 1e-5f);
        S1[j] = s; T1[j] = (bl1[j] - bn1m[j]) * s + bn1b[j];
      } else {
        int c = j - 256;
        float s = bn2w[c] * rsqrtf(bn2v[c] + 1e-5f);
        S2[c] = s; T2[c] = (bl2[c] - bn2m[c]) * s + bn2b[c];
      }
    }
  } else {
    // ---- x convert: f32 -> bf16 (xb) + fp8 (xq) ----
    int i = (blk - 2050) * 256 + threadIdx.x;
    if (i < NN * 128 / 4){
      float4 v = x[i];
      uint2 o; o.x = packbf2(v.x, v.y); o.y = packbf2(v.z, v.w);
      xb[i] = o;
      int w = 0;
      w = __builtin_amdgcn_cvt_pk_fp8_f32(v.x, v.y, w, false);
      w = __builtin_amdgcn_cvt_pk_fp8_f32(v.z, v.w, w, true);
      xq[i] = (unsigned)w;
    }
  }
}

// ---------------- mean aggregation (gather via fixed-slot CSR) ----------------
__global__ __launch_bounds__(256) void agg128q_k(const unsigned short* __restrict__ featq,
                         unsigned* __restrict__ out,
                         const int* __restrict__ cnt, const int* __restrict__ cslot){
  const int lane = threadIdx.x & 63;
  const int node0 = __builtin_amdgcn_readfirstlane(blockIdx.x * 4 + (threadIdx.x >> 6));
  const int nw = gridDim.x * 4;
  for (int node = node0; node < NN; node += nw){
    const int start = node << 6;
    const int deg = cnt[node];
    const int end = start + (deg < 64 ? deg : 64);
    float a0 = 0.f, a1 = 0.f, b0 = 0.f, b1 = 0.f;
    int e = start;
    for (; e + 7 < end; e += 8){
      unsigned u0 = featq[(size_t)cslot[e]     * 64 + lane];
      unsigned u1 = featq[(size_t)cslot[e + 1] * 64 + lane];
      unsigned u2 = featq[(size_t)cslot[e + 2] * 64 + lane];
      unsigned u3 = featq[(size_t)cslot[e + 3] * 64 + lane];
      unsigned u4 = featq[(size_t)cslot[e + 4] * 64 + lane];
      unsigned u5 = featq[(size_t)cslot[e + 5] * 64 + lane];
      unsigned u6 = featq[(size_t)cslot[e + 6] * 64 + lane];
      unsigned u7 = featq[(size_t)cslot[e + 7] * 64 + lane];
      a0 += __builtin_amdgcn_cvt_f32_fp8(u0, 0); a1 += __builtin_amdgcn_cvt_f32_fp8(u0, 1);
      b0 += __builtin_amdgcn_cvt_f32_fp8(u1, 0); b1 += __builtin_amdgcn_cvt_f32_fp8(u1, 1);
      a0 += __builtin_amdgcn_cvt_f32_fp8(u2, 0); a1 += __builtin_amdgcn_cvt_f32_fp8(u2, 1);
      b0 += __builtin_amdgcn_cvt_f32_fp8(u3, 0); b1 += __builtin_amdgcn_cvt_f32_fp8(u3, 1);
      a0 += __builtin_amdgcn_cvt_f32_fp8(u4, 0); a1 += __builtin_amdgcn_cvt_f32_fp8(u4, 1);
      b0 += __builtin_amdgcn_cvt_f32_fp8(u5, 0); b1 += __builtin_amdgcn_cvt_f32_fp8(u5, 1);
      a0 += __builtin_amdgcn_cvt_f32_fp8(u6, 0); a1 += __builtin_amdgcn_cvt_f32_fp8(u6, 1);
      b0 += __builtin_amdgcn_cvt_f32_fp8(u7, 0); b1 += __builtin_amdgcn_cvt_f32_fp8(u7, 1);
    }
    for (; e < end; ++e){
      unsigned u = featq[(size_t)cslot[e] * 64 + lane];
      a0 += __builtin_amdgcn_cvt_f32_fp8(u, 0); a1 += __builtin_amdgcn_cvt_f32_fp8(u, 1);
    }
    float inv = 1.f / (float)(deg > 0 ? deg : 1);
    out[(size_t)node * 64 + lane] = packbf2((a0 + b0) * inv, (a1 + b1) * inv);
  }
}

#define DEC8(u, x0, x1, x2, x3) { \
  x0 += __builtin_amdgcn_cvt_f32_fp8((u), 0); \
  x1 += __builtin_amdgcn_cvt_f32_fp8((u), 1); \
  x2 += __builtin_amdgcn_cvt_f32_fp8((u), 2); \
  x3 += __builtin_amdgcn_cvt_f32_fp8((u), 3); }

__global__ __launch_bounds__(256) void agg256q_k(const unsigned* __restrict__ featq, unsigned* __restrict__ out,
                         const int* __restrict__ cnt, const int* __restrict__ cslot){
  const int lane = threadIdx.x & 63;
  const int node0 = __builtin_amdgcn_readfirstlane(blockIdx.x * 4 + (threadIdx.x >> 6));
  const int nw = gridDim.x * 4;
  for (int node = node0; node < NN; node += nw){
    const int start = node << 6;
    const int deg = cnt[node];
    const int end = start + (deg < 64 ? deg : 64);
    float a0 = 0.f, a1 = 0.f, a2 = 0.f, a3 = 0.f;
    float b0 = 0.f, b1 = 0.f, b2 = 0.f, b3 = 0.f;
    int e = start;
    for (; e + 7 < end; e += 8){
      unsigned u0 = featq[(size_t)cslot[e]     * 64 + lane];
      unsigned u1 = featq[(size_t)cslot[e + 1] * 64 + lane];
      unsigned u2 = featq[(size_t)cslot[e + 2] * 64 + lane];
      unsigned u3 = featq[(size_t)cslot[e + 3] * 64 + lane];
      unsigned u4 = featq[(size_t)cslot[e + 4] * 64 + lane];
      unsigned u5 = featq[(size_t)cslot[e + 5] * 64 + lane];
      unsigned u6 = featq[(size_t)cslot[e + 6] * 64 + lane];
      unsigned u7 = featq[(size_t)cslot[e + 7] * 64 + lane];
      DEC8(u0, a0, a1, a2, a3) DEC8(u1, b0, b1, b2, b3)
      DEC8(u2, a0, a1, a2, a3) DEC8(u3, b0, b1, b2, b3)
      DEC8(u4, a0, a1, a2, a3) DEC8(u5, b0, b1, b2, b3)
      DEC8(u6, a0, a1, a2, a3) DEC8(u7, b0, b1, b2, b3)
    }
    for (; e < end; ++e){
      unsigned u = featq[(size_t)cslot[e] * 64 + lane];
      DEC8(u, a0, a1, a2, a3)
    }
    float inv = 1.f / (float)(deg > 0 ? deg : 1);
    uint2 o; o.x = packbf2((a0 + b0) * inv, (a1 + b1) * inv);
    o.y = packbf2((a2 + b2) * inv, (a3 + b3) * inv);
    *reinterpret_cast<uint2*>(out + (size_t)node * 128 + lane * 2) = o;
  }
}

// out[node][c] = ub(bf16) + mean(tq fp8 over in-edges) + bl3  (write-only on out)
__global__ __launch_bounds__(256) void final_k(const unsigned short* __restrict__ tq,
                        const unsigned* __restrict__ ub, float* __restrict__ out,
                        const int* __restrict__ cnt, const int* __restrict__ cslot,
                        const float* __restrict__ bl3){
  const int lane = threadIdx.x & 63;
  const int node0 = __builtin_amdgcn_readfirstlane(blockIdx.x * 4 + (threadIdx.x >> 6));
  const int nw = gridDim.x * 4;
  for (int node = node0; node < NN; node += nw){
    const int start = node << 6;
    const int deg = cnt[node];
    const int end = start + (deg < 64 ? deg : 64);
    float a0 = 0.f, a1 = 0.f, b0 = 0.f, b1 = 0.f;
    int e = start;
    for (; e + 7 < end; e += 8){
      unsigned u0 = tq[(size_t)cslot[e]     * 64 + lane];
      unsigned u1 = tq[(size_t)cslot[e + 1] * 64 + lane];
      unsigned u2 = tq[(size_t)cslot[e + 2] * 64 + lane];
      unsigned u3 = tq[(size_t)cslot[e + 3] * 64 + lane];
      unsigned u4 = tq[(size_t)cslot[e + 4] * 64 + lane];
      unsigned u5 = tq[(size_t)cslot[e + 5] * 64 + lane];
      unsigned u6 = tq[(size_t)cslot[e + 6] * 64 + lane];
      unsigned u7 = tq[(size_t)cslot[e + 7] * 64 + lane];
      a0 += __builtin_amdgcn_cvt_f32_fp8(u0, 0); a1 += __builtin_amdgcn_cvt_f32_fp8(u0, 1);
      b0 += __builtin_amdgcn_cvt_f32_fp8(u1, 0); b1 += __builtin_amdgcn_cvt_f32_fp8(u1, 1);
      a0 += __builtin_amdgcn_cvt_f32_fp8(u2, 0); a1 += __builtin_amdgcn_cvt_f32_fp8(u2, 1);
      b0 += __builtin_amdgcn_cvt_f32_fp8(u3, 0); b1 += __builtin_amdgcn_cvt_f32_fp8(u3, 1);
      a0 += __builtin_amdgcn_cvt_f32_fp8(u4, 0); a1 += __builtin_amdgcn_cvt_f32_fp8(u4, 1);
      b0 += __builtin_amdgcn_cvt_f32_fp8(u5, 0); b1 += __builtin_amdgcn_cvt_f32_fp8(u5, 1);
      a0 += __builtin_amdgcn_cvt_f32_fp8(u6, 0); a1 += __builtin_amdgcn_cvt_f32_fp8(u6, 1);
      b0 += __builtin_amdgcn_cvt_f32_fp8(u7, 0); b1 += __builtin_amdgcn_cvt_f32_fp8(u7, 1);
    }
    for (; e < end; ++e){
      unsigned u = tq[(size_t)cslot[e] * 64 + lane];
      a0 += __builtin_amdgcn_cvt_f32_fp8(u, 0); a1 += __builtin_amdgcn_cvt_f32_fp8(u, 1);
    }
    float inv = 1.f / (float)(deg > 0 ? deg : 1);
    unsigned uw = ub[(size_t)node * 64 + lane];
    float2 v;
    v.x = bflo(uw) + (a0 + b0) * inv + bl3[lane * 2];
    v.y = bfhi(uw) + (a1 + b1) * inv + bl3[lane * 2 + 1];
    *(reinterpret_cast<float2*>(out + (size_t)node * 128) + lane) = v;
  }
}

// ---------------- GEMM1 (round-8 structure, best measured) ----------------
template<int KTOT, int K0, int MODE>
__global__ __launch_bounds__(256) void gemm_k(
    const unsigned short* __restrict__ A0, const unsigned short* __restrict__ A1,
    const unsigned short* __restrict__ Bt,
    const float* __restrict__ S, const float* __restrict__ Tt,
    unsigned short* __restrict__ outB, unsigned char* __restrict__ outQ,
    float* __restrict__ outF, int M)
{
  __shared__ __align__(16) unsigned char lds[49152];   // 3 bufs x (A 8K | B 8K)
  const int tid = threadIdx.x;
  const int lane = tid & 63;
  const int wv = tid >> 6;
  const int wm = wv >> 1, wn = wv & 1;

  const int nwg = gridDim.x;
  const int q = nwg >> 3, r8 = nwg & 7;
  const int xcd = blockIdx.x & 7, idx = blockIdx.x >> 3;
  const int wg = (xcd < r8) ? xcd * (q + 1) + idx : r8 * (q + 1) + (xcd - r8) * q + idx;
  const int bm = wg >> 1, bn = wg & 1;

  const int rr0 = tid >> 2,         g0 = (tid & 3) ^ ((tid >> 3) & 3);
  const int rr1 = (tid + 256) >> 2, g1 = ((tid + 256) & 3) ^ (((tid + 256) >> 3) & 3);
  int growA0 = bm * 128 + rr0; if (growA0 > M - 1) growA0 = M - 1;
  int growA1 = bm * 128 + rr1; if (growA1 > M - 1) growA1 = M - 1;
  const size_t browA0 = (size_t)(bn * 128 + rr0) * KTOT;
  const size_t browA1 = (size_t)(bn * 128 + rr1) * KTOT;

  const int l15 = lane & 15, kg = lane >> 4;
  const int slot = (kg ^ ((l15 >> 1) & 3)) * 16;

  constexpr int NT = KTOT / 32;

  auto STAGE = [&](int buf, int kt){
    const int kb = kt * 32;
    const unsigned short* Ap; int pitch, kk;
    if (KTOT == K0 || kb < K0){ Ap = A0; pitch = K0; kk = kb; }
    else { Ap = A1; pitch = KTOT - K0; kk = kb - K0; }
    unsigned char* base = lds + buf * 16384;
    gload16(Ap + (size_t)growA0 * pitch + kk + g0 * 8, base + tid * 16);
    gload16(Ap + (size_t)growA1 * pitch + kk + g1 * 8, base + 4096 + tid * 16);
    gload16(Bt + browA0 + kb + g0 * 8, base + 8192 + tid * 16);
    gload16(Bt + browA1 + kb + g1 * 8, base + 12288 + tid * 16);
  };

  f32x4 acc[4][4];
  #pragma unroll
  for (int i = 0; i < 4; ++i)
    #pragma unroll
    for (int j = 0; j < 4; ++j){ acc[i][j][0]=0.f; acc[i][j][1]=0.f; acc[i][j][2]=0.f; acc[i][j][3]=0.f; }

  STAGE(0, 0);
  if (NT > 1) STAGE(1, 1);

  int rb = 0, sb = 2;
  for (int kt = 0; kt < NT; ++kt){
    if (kt < NT - 1) asm volatile("s_waitcnt vmcnt(4)" ::: "memory");
    else             asm volatile("s_waitcnt vmcnt(0)" ::: "memory");
    __builtin_amdgcn_s_barrier();
    __builtin_amdgcn_sched_barrier(0);

    if (kt + 2 < NT){ STAGE(sb, kt + 2); sb = (sb == 2) ? 0 : sb + 1; }

    unsigned char* base = lds + rb * 16384;
    rb = (rb == 2) ? 0 : rb + 1;

    bh8 af[4], bf[4];
    #pragma unroll
    for (int mi = 0; mi < 4; ++mi){
      int rA = wm * 64 + mi * 16 + l15;
      af[mi] = *reinterpret_cast<const bh8*>(base + rA * 64 + slot);
    }
    #pragma unroll
    for (int ni = 0; ni < 4; ++ni){
      int rB = wn * 64 + ni * 16 + l15;
      bf[ni] = *reinterpret_cast<const bh8*>(base + 8192 + rB * 64 + slot);
    }
    __builtin_amdgcn_s_setprio(1);
    #pragma unroll
    for (int mi = 0; mi < 4; ++mi)
      #pragma unroll
      for (int ni = 0; ni < 4; ++ni)
        acc[mi][ni] = __builtin_amdgcn_mfma_f32_16x16x32_bf16(af[mi], bf[ni], acc[mi][ni], 0, 0, 0);
    __builtin_amdgcn_s_setprio(0);
  }

  #pragma unroll
  for (int mi = 0; mi < 4; ++mi){
    int rbase = bm * 128 + wm * 64 + mi * 16 + ((lane >> 4) << 2);
    #pragma unroll
    for (int ni = 0; ni < 4; ++ni){
      int col = bn * 128 + wn * 64 + ni * 16 + (lane & 15);
      #pragma unroll
      for (int j = 0; j < 4; ++j){
        int row = rbase + j;
        if (row < M){
          float v = acc[mi][ni][j];
          if (MODE == 0){
            v = v * S[col] + Tt[col];
            v = v > 0.f ? v : 0.f;
            outB[(size_t)row * 256 + col] = f2bf(v);
            if (outQ) outQ[(size_t)row * 256 + col] = f2fp8(v);
          } else {
            if (col < 128) outQ[(size_t)row * 128 + col] = f2fp8(v);
            else           outF[(size_t)row * 128 + (col - 128)] = v;
          }
        }
      }
    }
  }
}

// ---------------- FUSED layer-2 + layer-3 GEMM (round-13/15 structure) ----------------
__global__ __launch_bounds__(256) void gemm23_k(
    const unsigned short* __restrict__ A0 /*agg2 [NN][256]*/,
    const unsigned short* __restrict__ A1 /*h1   [NN][256]*/,
    const unsigned short* __restrict__ B2 /*B2t [256][512]*/,
    const unsigned short* __restrict__ B3 /*B3t [256][256]*/,
    const float* __restrict__ S, const float* __restrict__ Tt,
    unsigned char* __restrict__ tq, unsigned short* __restrict__ ub, int M)
{
  __shared__ __align__(16) unsigned char lds[61440];  // 3 bufs x 20KB; h2 tile 32KB overlays bufs 0-1
  const int tid = threadIdx.x;
  const int lane = tid & 63;
  const int wv = tid >> 6;                 // wave owns cols wv*64..wv*64+63

  const int nwg = gridDim.x;
  const int q = nwg >> 3, r8 = nwg & 7;
  const int xcd = blockIdx.x & 7, idx = blockIdx.x >> 3;
  const int bm = (xcd < r8) ? xcd * (q + 1) + idx : r8 * (q + 1) + (xcd - r8) * q + idx;

  const int l15 = lane & 15, kg = lane >> 4;
  const int slot = (kg ^ ((l15 >> 1) & 3)) * 16;
  const int rr = tid >> 2;                              // 0..63
  const int g  = (tid & 3) ^ ((tid >> 3) & 3);          // swizzled source chunk
  int grow = bm * 64 + rr; if (grow > M - 1) grow = M - 1;

  auto STAGE = [&](int buf, int kt){
    const int kb = kt * 32;
    const unsigned short* Ap = (kb < 256) ? A0 : A1;
    const int kk = (kb < 256) ? kb : kb - 256;
    unsigned char* base = lds + buf * 20480;
    gload16(Ap + (size_t)grow * 256 + kk + g * 8, base + tid * 16);              // A 4KB
    gload16(B2 + (size_t)(rr      ) * 512 + kb + g * 8, base +  4096 + tid * 16); // B 16KB
    gload16(B2 + (size_t)(rr +  64) * 512 + kb + g * 8, base +  8192 + tid * 16);
    gload16(B2 + (size_t)(rr + 128) * 512 + kb + g * 8, base + 12288 + tid * 16);
    gload16(B2 + (size_t)(rr + 192) * 512 + kb + g * 8, base + 16384 + tid * 16);
  };

  f32x4 acc[4][4];
  #pragma unroll
  for (int i = 0; i < 4; ++i)
    #pragma unroll
    for (int j = 0; j < 4; ++j){ acc[i][j][0]=0.f; acc[i][j][1]=0.f; acc[i][j][2]=0.f; acc[i][j][3]=0.f; }

  STAGE(0, 0);
  STAGE(1, 1);

  int rb = 0, sb = 2;
  #pragma unroll 1
  for (int kt = 0; kt < 16; ++kt){
    if (kt < 15) asm volatile("s_waitcnt vmcnt(5)" ::: "memory");
    else         asm volatile("s_waitcnt vmcnt(0)" ::: "memory");
    __builtin_amdgcn_s_barrier();
    __builtin_amdgcn_sched_barrier(0);

    if (kt + 2 < 16){ STAGE(sb, kt + 2); sb = (sb == 2) ? 0 : sb + 1; }

    unsigned char* base = lds + rb * 20480;
    rb = (rb == 2) ? 0 : rb + 1;

    bh8 af[4], bf[4];
    #pragma unroll
    for (int mi = 0; mi < 4; ++mi)
      af[mi] = *reinterpret_cast<const bh8*>(base + (mi * 16 + l15) * 64 + slot);
    #pragma unroll
    for (int ni = 0; ni < 4; ++ni)
      bf[ni] = *reinterpret_cast<const bh8*>(base + 4096 + (wv * 64 + ni * 16 + l15) * 64 + slot);

    __builtin_amdgcn_s_setprio(1);
    #pragma unroll
    for (int mi = 0; mi < 4; ++mi)
      #pragma unroll
      for (int ni = 0; ni < 4; ++ni)   // SWAPPED operands: value = h2[m=l15-side][n=reg-side]
        acc[mi][ni] = __builtin_amdgcn_mfma_f32_16x16x32_bf16(bf[ni], af[mi], acc[mi][ni], 0, 0, 0);
    __builtin_amdgcn_s_setprio(0);
  }

  // ---- phase transition: h2 tile -> LDS [64 rows][256 cols] bf16, swizzled ----
  __syncthreads();
  #pragma unroll
  for (int mi = 0; mi < 4; ++mi){
    const int row = mi * 16 + l15;
    #pragma unroll
    for (int ni = 0; ni < 4; ++ni){
      const int c0 = wv * 64 + ni * 16 + kg * 4;    // first of 4 consecutive cols
      float v0 = acc[mi][ni][0] * S[c0]     + Tt[c0];     v0 = v0 > 0.f ? v0 : 0.f;
      float v1 = acc[mi][ni][1] * S[c0 + 1] + Tt[c0 + 1]; v1 = v1 > 0.f ? v1 : 0.f;
      float v2 = acc[mi][ni][2] * S[c0 + 2] + Tt[c0 + 2]; v2 = v2 > 0.f ? v2 : 0.f;
      float v3 = acc[mi][ni][3] * S[c0 + 3] + Tt[c0 + 3]; v3 = v3 > 0.f ? v3 : 0.f;
      uint2 w; w.x = packbf2(v0, v1); w.y = packbf2(v2, v3);
      const int chunk = wv * 8 + ni * 2 + (kg >> 1);      // 16B chunk index 0..31
      const int byte = row * 512 + ((chunk ^ (row & 7)) * 16) + (kg & 1) * 8;
      *reinterpret_cast<uint2*>(lds + byte) = w;
    }
  }
  __syncthreads();

  // ---- phase 2: out = h2_tile @ B3t^T (K = 256) ----
  f32x4 acc2[4][4];
  #pragma unroll
  for (int i = 0; i < 4; ++i)
    #pragma unroll
    for (int j = 0; j < 4; ++j){ acc2[i][j][0]=0.f; acc2[i][j][1]=0.f; acc2[i][j][2]=0.f; acc2[i][j][3]=0.f; }

  #pragma unroll 1
  for (int kt = 0; kt < 8; ++kt){
    const int kb = kt * 32;
    bh8 af2[4], bf2[4];
    #pragma unroll
    for (int mi = 0; mi < 4; ++mi){
      const int row = mi * 16 + l15;
      const int chunk = kt * 4 + kg;
      af2[mi] = *reinterpret_cast<const bh8*>(lds + row * 512 + ((chunk ^ (row & 7)) * 16));
    }
    #pragma unroll
    for (int ni = 0; ni < 4; ++ni)
      bf2[ni] = *reinterpret_cast<const bh8*>(B3 + (size_t)(wv * 64 + ni * 16 + l15) * 256 + kb + kg * 8);
    __builtin_amdgcn_s_setprio(1);
    #pragma unroll
    for (int mi = 0; mi < 4; ++mi)
      #pragma unroll
      for (int ni = 0; ni < 4; ++ni)
        acc2[mi][ni] = __builtin_amdgcn_mfma_f32_16x16x32_bf16(af2[mi], bf2[ni], acc2[mi][ni], 0, 0, 0);
    __builtin_amdgcn_s_setprio(0);
  }

  #pragma unroll
  for (int mi = 0; mi < 4; ++mi){
    const int rbase = bm * 64 + mi * 16 + (kg << 2);
    #pragma unroll
    for (int ni = 0; ni < 4; ++ni){
      const int col = wv * 64 + ni * 16 + l15;
      #pragma unroll
      for (int j = 0; j < 4; ++j){
        const int row = rbase + j;
        if (row < M){
          float v = acc2[mi][ni][j];
          if (col < 128) tq[(size_t)row * 128 + col] = f2fp8(v);
          else           ub[(size_t)row * 128 + (col - 128)] = f2bf(v);
        }
      }
    }
  }
}

// ---------------- launch ----------------
extern "C" void kernel_launch(void* const* d_in, const int* in_sizes, int n_in,
                              void* d_out, int out_size, void* d_ws, size_t ws_size,
                              hipStream_t stream) {
  (void)in_sizes; (void)n_in; (void)out_size; (void)ws_size;
  const float* x   = (const float*)d_in[0];
  const int*   ei  = (const int*)d_in[1];
  const int*   srcv = ei;
  const int*   dstv = ei + NE;
  const float* wl1 = (const float*)d_in[2];
  const float* bl1 = (const float*)d_in[3];
  const float* wr1 = (const float*)d_in[4];
  const float* wl2 = (const float*)d_in[5];
  const float* bl2 = (const float*)d_in[6];
  const float* wr2 = (const float*)d_in[7];
  const float* wl3 = (const float*)d_in[8];
  const float* bl3 = (const float*)d_in[9];
  const float* wr3 = (const float*)d_in[10];
  const float* bn1w = (const float*)d_in[11];
  const float* bn1b = (const float*)d_in[12];
  const float* bn1m = (const float*)d_in[13];
  const float* bn1v = (const float*)d_in[14];
  const float* bn2w = (const float*)d_in[15];
  const float* bn2b = (const float*)d_in[16];
  const float* bn2m = (const float*)d_in[17];
  const float* bn2v = (const float*)d_in[18];

  char* ws = (char*)d_ws;
  size_t off = 0;
  auto alloc = [&](size_t bytes) -> void* {
    void* p = ws + off;
    off += (bytes + 255) & ~(size_t)255;
    return p;
  };
  int* cnt   = (int*)alloc((size_t)NN * 4);
  int* cslot = (int*)alloc((size_t)NN * 64 * 4);   // fixed 64-slot bins per node
  unsigned short* B1t = (unsigned short*)alloc(256 * 256 * 2);
  unsigned short* B2t = (unsigned short*)alloc(256 * 512 * 2);
  unsigned short* B3t = (unsigned short*)alloc(256 * 256 * 2);
  float* S1 = (float*)alloc(256 * 4);
  float* T1 = (float*)alloc(256 * 4);
  float* S2 = (float*)alloc(256 * 4);
  float* T2 = (float*)alloc(256 * 4);
  unsigned short* xb   = (unsigned short*)alloc((size_t)NN * 128 * 2); // agg2 lo half after GEMM1
  unsigned short* agg1 = (unsigned short*)alloc((size_t)NN * 128 * 2); // agg2 hi half after GEMM1
  unsigned short* h1   = (unsigned short*)alloc((size_t)NN * 256 * 2);
  unsigned short* h2   = (unsigned short*)alloc((size_t)NN * 256 * 2); // staging region (h2 never materialized)
  // Overlay lifetimes (stream-ordered):
  //   agg2 spans xb+agg1 — both dead after gemm1 reads them.
  //   h1q = h2 bytes [0 : NN*256)              : gemm1 epilogue out, read by
  //     agg256q, dead before gemm23 starts.
  //   xq  = h2 bytes [NN*256 : NN*256+NN*128)  : pre_k out, read by agg128q, dead after.
  //   tq  = h2 bytes [0 : NN*128)              : gemm23 phase-2 out, read by final.
  //   ub  = h2 bytes [NN*256 : NN*256+NN*256)  : gemm23 phase-2 out (bf16 u),
  //     read by final. Overlays dead xq; disjoint from tq.
  //   NONE of tq/ub on h1 — gemm23 reads h1 as A1 concurrently!
  unsigned short* agg2 = xb;
  unsigned char*  h1q  = (unsigned char*)h2;
  unsigned*       xq   = (unsigned*)((unsigned char*)h2 + (size_t)NN * 256);
  unsigned char*  tq   = (unsigned char*)h2;
  unsigned short* ub   = (unsigned short*)((unsigned char*)h2 + (size_t)NN * 256);
  float* outp = (float*)d_out;

  hipMemsetAsync(cnt, 0, (size_t)NN * 4, stream);
  // fused pre-chain: CSR build (1024 blocks) + prep (1026) + f2b (6250)
  pre_k<<<8300, 256, 0, stream>>>(srcv, dstv, cnt, cslot,
                                  (const float4*)x, (uint2*)xb, xq,
                                  wl1, wr1, wl2, wr2, wl3, wr3, bl1, bl2,
                                  bn1w, bn1b, bn1m, bn1v, bn2w, bn2b, bn2m, bn2v,
                                  B1t, B2t, B3t, S1, T1, S2, T2);

  // layer 1: gather fp8 x, GEMM writes h1 bf16 + h1q fp8 (fused conversion)
  agg128q_k<<<AGG_BLOCKS, 256, 0, stream>>>((const unsigned short*)xq, (unsigned*)agg1, cnt, cslot);
  gemm_k<256, 128, 0><<<782, 256, 0, stream>>>(agg1, xb, B1t, S1, T1, h1, h1q, nullptr, NN);
  // layer 2 gather (fp8 h1), then FUSED layer-2+3 GEMM (h2 stays in LDS)
  agg256q_k<<<AGG_BLOCKS, 256, 0, stream>>>((const unsigned*)h1q, (unsigned*)agg2, cnt, cslot);
  gemm23_k<<<782, 256, 0, stream>>>(agg2, h1, B2t, B3t, S2, T2, tq, ub, NN);
  final_k<<<AGG_BLOCKS, 256, 0, stream>>>((const unsigned short*)tq, (const unsigned*)ub, outp, cnt, cslot, bl3);
}